// Round 4
// baseline (269.757 us; speedup 1.0000x reference)
//
#include <hip/hip_runtime.h>

#define S_LEN 2048
#define D_DIM 1024
#define NH    16
#define DHEAD 64

typedef float f32x4 __attribute__((ext_vector_type(4)));
typedef __bf16 bf16x8 __attribute__((ext_vector_type(8)));
typedef unsigned short u16;
typedef unsigned int u32;
typedef unsigned short u16x8 __attribute__((ext_vector_type(8)));
typedef unsigned short u16x4 __attribute__((ext_vector_type(4)));

__device__ __forceinline__ u16 f2bf(float f) {
    union { float f; unsigned u; } c; c.f = f;
    unsigned u = c.u + 0x7fffu + ((c.u >> 16) & 1u);
    return (u16)(u >> 16);
}

#if __has_builtin(__builtin_amdgcn_exp2f)
#define EXP2(x) __builtin_amdgcn_exp2f(x)
#else
#define EXP2(x) exp2f(x)
#endif

// 0.25*log2(e), 0.125*log2(e)
#define C_QK  0.36067376022224085f
#define C_SQ  0.18033688011112043f

#define MFMA16(a, b, c) __builtin_amdgcn_mfma_f32_16x16x32_bf16((a), (b), (c), 0, 0, 0)

// pack two f32 into bf16 pair (truncation; bias cancels in softmax normalize)
__device__ __forceinline__ u32 pack_bf(float lo, float hi) {
    union { float f; u32 u; } a, b; a.f = lo; b.f = hi;
    return (b.u & 0xFFFF0000u) | (a.u >> 16);
}

// ---------------------------------------------------------------------------
// M[h,j,f] = 0.125 * sum_e Wq[e, h*64+j] * Wv[e, h*64+f]
__global__ __launch_bounds__(256) void k_precomp_M(
    const float* __restrict__ Wq, const float* __restrict__ Wv, float* __restrict__ M) {
    __shared__ float red[4][8][64];
    const int tid = threadIdx.x;
    const int f = tid & 63, ks = tid >> 6;
    const int jg = blockIdx.x, h = blockIdx.y;
    const float* vcol = Wv + h * DHEAD + f;
    const float* qcol = Wq + h * DHEAD + jg * 8;
    float acc[8];
#pragma unroll
    for (int jj = 0; jj < 8; ++jj) acc[jj] = 0.f;
    const int e0 = ks * 256;
    for (int e = e0; e < e0 + 256; ++e) {
        float v = vcol[(size_t)e * D_DIM];
        const float* qr = qcol + (size_t)e * D_DIM;
#pragma unroll
        for (int jj = 0; jj < 8; ++jj) acc[jj] += qr[jj] * v;
    }
#pragma unroll
    for (int jj = 0; jj < 8; ++jj) red[ks][jj][f] = acc[jj];
    __syncthreads();
    for (int t = tid; t < 512; t += 256) {
        int jj = t >> 6, ff = t & 63;
        float s = red[0][jj][ff] + red[1][jj][ff] + red[2][jj][ff] + red[3][jj][ff];
        M[((size_t)(h * 64 + jg * 8 + jj)) * 64 + ff] = s * 0.125f;
    }
}

// ---------------------------------------------------------------------------
// W2[o, h*64+j] = sum_f M[h,j,f] * Wout[o, h*64+f]   (bf16 out)
__global__ __launch_bounds__(256) void k_precomp_W2(
    const float* __restrict__ M, const float* __restrict__ Wout, u16* __restrict__ W2) {
    __shared__ float Ms[64][65];
    __shared__ float Ws[64][65];
    const int tid = threadIdx.x;
    const int ob = blockIdx.x, h = blockIdx.y;
    {
        int rr = tid >> 2, seg = tid & 3;
        const float* ms = M + ((size_t)(h * 64 + rr)) * 64 + seg * 16;
        const float* ws = Wout + (size_t)(ob * 64 + rr) * D_DIM + h * DHEAD + seg * 16;
#pragma unroll
        for (int e = 0; e < 16; ++e) {
            Ms[rr][seg * 16 + e] = ms[e];
            Ws[rr][seg * 16 + e] = ws[e];
        }
    }
    __syncthreads();
    int j = tid & 63, o0 = (tid >> 6) * 16;
    for (int oo = o0; oo < o0 + 16; ++oo) {
        float acc = 0.f;
#pragma unroll
        for (int f = 0; f < 64; ++f) acc += Ms[j][f] * Ws[oo][f];
        W2[(size_t)(ob * 64 + oo) * D_DIM + h * DHEAD + j] = f2bf(acc);
    }
}

// ---------------------------------------------------------------------------
// Q projection (fp32 in, converts in staging) + side-products.
__global__ __launch_bounds__(256) void k_qproj(
    const float* __restrict__ x, const float* __restrict__ Wq,
    const float* __restrict__ bq, const int* __restrict__ mask,
    u16* __restrict__ Qbf, u16* __restrict__ QT, float* __restrict__ sq05) {
    __shared__ u16 Al[128][36];
    __shared__ u16 Bl[128][36];
    const int tid = threadIdx.x, lane = tid & 63, w = tid >> 6;
    const int wm = w & 1, wn = w >> 1;
    const int col16 = lane & 15, quad = lane >> 4;
    const int bm = blockIdx.x, bn = blockIdx.y;

    f32x4 acc[4][4];
    const f32x4 z4 = {0.f, 0.f, 0.f, 0.f};
#pragma unroll
    for (int i = 0; i < 4; ++i)
#pragma unroll
        for (int j = 0; j < 4; ++j) acc[i][j] = z4;

    const int r = tid >> 1, hf = tid & 1;
    const float* pa = x + (size_t)(bm * 128 + r) * D_DIM + hf * 16;
    const float* pb = Wq + (size_t)(bn * 128 + r) * D_DIM + hf * 16;

    f32x4 a0 = *(const f32x4*)(pa),      a1 = *(const f32x4*)(pa + 4);
    f32x4 a2 = *(const f32x4*)(pa + 8),  a3 = *(const f32x4*)(pa + 12);
    f32x4 b0 = *(const f32x4*)(pb),      b1 = *(const f32x4*)(pb + 4);
    f32x4 b2 = *(const f32x4*)(pb + 8),  b3 = *(const f32x4*)(pb + 12);

    for (int k0 = 0; k0 < D_DIM; k0 += 32) {
        u16x8 wa0, wa1, wb0, wb1;
#pragma unroll
        for (int e = 0; e < 4; ++e) {
            wa0[e] = f2bf(a0[e]); wa0[e + 4] = f2bf(a1[e]);
            wa1[e] = f2bf(a2[e]); wa1[e + 4] = f2bf(a3[e]);
            wb0[e] = f2bf(b0[e]); wb0[e + 4] = f2bf(b1[e]);
            wb1[e] = f2bf(b2[e]); wb1[e + 4] = f2bf(b3[e]);
        }
        __syncthreads();
        *(u16x8*)&Al[r][hf * 16]     = wa0;
        *(u16x8*)&Al[r][hf * 16 + 8] = wa1;
        *(u16x8*)&Bl[r][hf * 16]     = wb0;
        *(u16x8*)&Bl[r][hf * 16 + 8] = wb1;
        __syncthreads();
        if (k0 + 32 < D_DIM) {
            a0 = *(const f32x4*)(pa + k0 + 32); a1 = *(const f32x4*)(pa + k0 + 36);
            a2 = *(const f32x4*)(pa + k0 + 40); a3 = *(const f32x4*)(pa + k0 + 44);
            b0 = *(const f32x4*)(pb + k0 + 32); b1 = *(const f32x4*)(pb + k0 + 36);
            b2 = *(const f32x4*)(pb + k0 + 40); b3 = *(const f32x4*)(pb + k0 + 44);
        }
        bf16x8 af[4];
#pragma unroll
        for (int mt = 0; mt < 4; ++mt)
            af[mt] = *(const bf16x8*)&Al[wm * 64 + mt * 16 + col16][quad * 8];
#pragma unroll
        for (int nt = 0; nt < 4; ++nt) {
            bf16x8 bfr = *(const bf16x8*)&Bl[wn * 64 + nt * 16 + col16][quad * 8];
#pragma unroll
            for (int mt = 0; mt < 4; ++mt)
                acc[mt][nt] = MFMA16(af[mt], bfr, acc[mt][nt]);
        }
    }

    const int h = bn * 2 + wn;
    f32x4 ssum[4];
#pragma unroll
    for (int mt = 0; mt < 4; ++mt) ssum[mt] = z4;

#pragma unroll
    for (int nt = 0; nt < 4; ++nt) {
        int col = bn * 128 + wn * 64 + nt * 16 + col16;
        int dloc = nt * 16 + col16;
        float bqv = bq[col];
#pragma unroll
        for (int mt = 0; mt < 4; ++mt) {
            int row0 = bm * 128 + wm * 64 + mt * 16 + quad * 4;
            int b = row0 >> 11, smod0 = row0 & 2047;
            u16x4 pk;
#pragma unroll
            for (int rr = 0; rr < 4; ++rr) {
                float qv = acc[mt][nt][rr] + bqv;
                ssum[mt][rr] += qv * qv;
                u16 bv = f2bf(qv);
                pk[rr] = bv;
                Qbf[(size_t)(row0 + rr) * D_DIM + col] = bv;
            }
            *(u16x4*)(QT + ((size_t)(b * NH + h) * DHEAD + dloc) * S_LEN + smod0) = pk;
        }
    }
#pragma unroll
    for (int mt = 0; mt < 4; ++mt) {
        int row0 = bm * 128 + wm * 64 + mt * 16 + quad * 4;
        int b = row0 >> 11, smod0 = row0 & 2047;
#pragma unroll
        for (int rr = 0; rr < 4; ++rr) {
            float v = ssum[mt][rr];
            v += __shfl_xor(v, 1); v += __shfl_xor(v, 2);
            v += __shfl_xor(v, 4); v += __shfl_xor(v, 8);
            if (col16 == 0) {
                int sidx = smod0 + rr;
                float out = mask[b * S_LEN + sidx] ? v * C_SQ : 1e30f;
                sq05[((size_t)(b * NH + h)) * S_LEN + sidx] = out;
            }
        }
    }
}

// ---------------------------------------------------------------------------
// Fused L2 attention, transpose-free (S^T = K Q^T with permuted key rows so
// the exp'd C-layout registers ARE the PV B-fragments). Block = (b,h,qt128),
// 4 waves: wq = q-half (64 q), wk = key-half (64 of each 128-key tile).
__global__ __launch_bounds__(256, 2) void k_flash(
    const u16* __restrict__ Qbf, const u16* __restrict__ QT,
    const float* __restrict__ sq05, u16* __restrict__ attnO) {
    __shared__ __align__(16) char smem[34816];
    u16* Kt  = (u16*)smem;              // [128][64] u16, xor-swizzled cols
    u16* KtT = (u16*)(smem + 16384);    // [64][128] u16, xor-swizzled cols
    float* sql = (float*)(smem + 32768);// [128]

    const int tid = threadIdx.x, lane = tid & 63, w = tid >> 6;
    const int col16 = lane & 15, quad = lane >> 4;
    const int wq = w & 1, wk = w >> 1;
    const int qt = blockIdx.x & 15;
    const int h = (blockIdx.x >> 4) & 15;
    const int b = blockIdx.x >> 8;
    const u16* qbase = Qbf + (size_t)b * S_LEN * D_DIM + h * DHEAD;
    const u16* qtbase = QT + ((size_t)(b * NH + h)) * DHEAD * S_LEN;
    const float* sqb = sq05 + ((size_t)(b * NH + h)) * S_LEN;

    // loop-invariant Q^T B-fragments (global, once)
    bf16x8 qb[4][2];
#pragma unroll
    for (int nq = 0; nq < 4; ++nq)
#pragma unroll
        for (int k0 = 0; k0 < 2; ++k0)
            qb[nq][k0] = *(const bf16x8*)(qbase +
                (size_t)(qt * 128 + wq * 64 + nq * 16 + col16) * D_DIM + k0 * 32 + quad * 8);

    // per-kb Kt read offsets (u16 index) with key permutation + swizzle
    int krow[4], sqoff[4];
#pragma unroll
    for (int kb = 0; kb < 4; ++kb) {
        int r = wk * 64 + (kb >> 1) * 32 + (col16 >> 2) * 8 + (kb & 1) * 4 + (col16 & 3);
        int swz = (r & 3) | (((r >> 3) & 1) << 2);
        krow[kb] = r * 64 + (quad ^ swz) * 8;          // k0=0 block; k0=1 = ^32
        sqoff[kb] = wk * 64 + (kb >> 1) * 32 + quad * 8 + (kb & 1) * 4;
    }
    // per-dblk KtT read offsets
    int vrow[4];
#pragma unroll
    for (int dblk = 0; dblk < 4; ++dblk) {
        int rT = dblk * 16 + col16;
        vrow[dblk] = rT * 128 + ((wk * 8 + quad) ^ (rT & 7)) * 8;  // kt=0; kt=1 = ^32
    }

    // staging assignments
    const int kr = tid >> 1, ks = tid & 1;
    const int td = tid >> 2, ts = tid & 3;
    const int kswz = (kr & 3) | (((kr >> 3) & 1) << 2);
    const int tswz = td & 7;
    const u16* ksrc = qbase + (size_t)kr * D_DIM + ks * 32;
    const u16* tsrc = qtbase + (size_t)td * S_LEN + ts * 32;

    u16x8 pk[4], pt[4];
    float sv = 0.f;
#pragma unroll
    for (int i = 0; i < 4; ++i) pk[i] = *(const u16x8*)(ksrc + i * 8);
#pragma unroll
    for (int i = 0; i < 4; ++i) pt[i] = *(const u16x8*)(tsrc + i * 8);
    if (tid < 128) sv = sqb[tid];

    f32x4 Oacc[4][4], lacc[4];
    const f32x4 z4 = {0.f, 0.f, 0.f, 0.f};
#pragma unroll
    for (int d = 0; d < 4; ++d) {
        lacc[d] = z4;
#pragma unroll
        for (int n = 0; n < 4; ++n) Oacc[d][n] = z4;
    }
    bf16x8 ones;
    {
        union { u16x8 u; bf16x8 b; } cv;
#pragma unroll
        for (int e = 0; e < 8; ++e) cv.u[e] = 0x3F80;
        ones = cv.b;
    }

    for (int j = 0; j < S_LEN / 128; ++j) {
        __syncthreads();
#pragma unroll
        for (int i = 0; i < 4; ++i)
            *(u16x8*)(Kt + kr * 64 + ((ks * 4 + i) ^ kswz) * 8) = pk[i];
#pragma unroll
        for (int i = 0; i < 4; ++i)
            *(u16x8*)(KtT + td * 128 + ((ts * 4 + i) ^ tswz) * 8) = pt[i];
        if (tid < 128) sql[tid] = sv;
        __syncthreads();

        int jn = (j + 1) & 15;
        {
            const u16* kn = ksrc + (size_t)jn * 128 * D_DIM;
            const u16* tn = tsrc + (size_t)jn * 128;
#pragma unroll
            for (int i = 0; i < 4; ++i) pk[i] = *(const u16x8*)(kn + i * 8);
#pragma unroll
            for (int i = 0; i < 4; ++i) pt[i] = *(const u16x8*)(tn + i * 8);
            if (tid < 128) sv = sqb[jn * 128 + tid];
        }

        // S^T = K(permuted) · Q^T : per wave 64 keys x 64 q
        f32x4 sacc[4][4];
#pragma unroll
        for (int kb = 0; kb < 4; ++kb)
#pragma unroll
            for (int nq = 0; nq < 4; ++nq) sacc[kb][nq] = z4;
#pragma unroll
        for (int kb = 0; kb < 4; ++kb) {
            bf16x8 a0 = *(const bf16x8*)(Kt + krow[kb]);
            bf16x8 a1 = *(const bf16x8*)(Kt + (krow[kb] ^ 32));
#pragma unroll
            for (int nq = 0; nq < 4; ++nq) {
                sacc[kb][nq] = MFMA16(a0, qb[nq][0], sacc[kb][nq]);
                sacc[kb][nq] = MFMA16(a1, qb[nq][1], sacc[kb][nq]);
            }
        }

        // exp + pack: C-layout registers become PV B-fragments directly
        u32 pf[2][4][4];
#pragma unroll
        for (int kb = 0; kb < 4; ++kb) {
            f32x4 sqv = *(const f32x4*)(sql + sqoff[kb]);
            const int kt = kb >> 1, rb = (kb & 1) * 2;
#pragma unroll
            for (int nq = 0; nq < 4; ++nq) {
                float p0 = EXP2(fmaf(sacc[kb][nq][0], C_QK, -sqv[0]));
                float p1 = EXP2(fmaf(sacc[kb][nq][1], C_QK, -sqv[1]));
                float p2 = EXP2(fmaf(sacc[kb][nq][2], C_QK, -sqv[2]));
                float p3 = EXP2(fmaf(sacc[kb][nq][3], C_QK, -sqv[3]));
                pf[kt][nq][rb]     = pack_bf(p0, p1);
                pf[kt][nq][rb + 1] = pack_bf(p2, p3);
            }
        }

        // O^T += V^T · P^T ; lsum += ones · P^T
#pragma unroll
        for (int kt = 0; kt < 2; ++kt) {
            bf16x8 va[4];
#pragma unroll
            for (int dblk = 0; dblk < 4; ++dblk)
                va[dblk] = *(const bf16x8*)(KtT + (vrow[dblk] ^ (kt * 32)));
#pragma unroll
            for (int nq = 0; nq < 4; ++nq) {
                union { u32 u[4]; bf16x8 b; } pb;
#pragma unroll
                for (int i = 0; i < 4; ++i) pb.u[i] = pf[kt][nq][i];
                lacc[nq] = MFMA16(ones, pb.b, lacc[nq]);
#pragma unroll
                for (int dblk = 0; dblk < 4; ++dblk)
                    Oacc[dblk][nq] = MFMA16(va[dblk], pb.b, Oacc[dblk][nq]);
            }
        }
    }

    // cross-wave (key-half) combine + epilogue
    __syncthreads();
    float* Obuf = (float*)smem;                 // [2][16][64] f32x4
    float* lred = (float*)(smem + 32768);       // [2][4][64]
    if (wk == 1) {
#pragma unroll
        for (int dblk = 0; dblk < 4; ++dblk)
#pragma unroll
            for (int nq = 0; nq < 4; ++nq)
                *(f32x4*)(Obuf + ((wq * 16 + dblk * 4 + nq) * 64 + lane) * 4) = Oacc[dblk][nq];
#pragma unroll
        for (int nq = 0; nq < 4; ++nq)
            lred[(wq * 4 + nq) * 64 + lane] = lacc[nq][0];
    }
    __syncthreads();
    if (wk == 0) {
        float rinv[4];
#pragma unroll
        for (int nq = 0; nq < 4; ++nq)
            rinv[nq] = 1.f / (lacc[nq][0] + lred[(wq * 4 + nq) * 64 + lane]);
        u16* obase = attnO + (size_t)b * S_LEN * D_DIM + h * DHEAD;
#pragma unroll
        for (int dblk = 0; dblk < 4; ++dblk)
#pragma unroll
            for (int nq = 0; nq < 4; ++nq) {
                f32x4 o = Oacc[dblk][nq] + *(const f32x4*)(Obuf + ((wq * 16 + dblk * 4 + nq) * 64 + lane) * 4);
                int q = qt * 128 + wq * 64 + nq * 16 + col16;
                u16x4 pkk;
#pragma unroll
                for (int rr = 0; rr < 4; ++rr) pkk[rr] = f2bf(o[rr] * rinv[nq]);
                *(u16x4*)(obase + (size_t)q * D_DIM + dblk * 16 + quad * 4) = pkk;
            }
    }
}

// ---------------------------------------------------------------------------
// Output GEMM: out[s,o] = x[s,o] + bout[o] + sum_c attnO[s,c] * W2[o,c]
__global__ __launch_bounds__(256) void k_oproj(
    const u16* __restrict__ attnO, const u16* __restrict__ W2,
    const float* __restrict__ x, const float* __restrict__ bout, float* __restrict__ out) {
    __shared__ u16 Al[128][36];
    __shared__ u16 Bl[128][36];
    const int tid = threadIdx.x, lane = tid & 63, w = tid >> 6;
    const int wm = w & 1, wn = w >> 1;
    const int col16 = lane & 15, quad = lane >> 4;
    const int bm = blockIdx.x, bn = blockIdx.y;

    f32x4 acc[4][4];
    const f32x4 z4 = {0.f, 0.f, 0.f, 0.f};
#pragma unroll
    for (int i = 0; i < 4; ++i)
#pragma unroll
        for (int j = 0; j < 4; ++j) acc[i][j] = z4;

    const int r = tid >> 1, hf = tid & 1;
    const u16* pa = attnO + (size_t)(bm * 128 + r) * D_DIM + hf * 16;
    const u16* pb = W2 + (size_t)(bn * 128 + r) * D_DIM + hf * 16;

    u16x8 ra0 = *(const u16x8*)(pa),     ra1 = *(const u16x8*)(pa + 8);
    u16x8 rb0 = *(const u16x8*)(pb),     rb1 = *(const u16x8*)(pb + 8);

    for (int k0 = 0; k0 < D_DIM; k0 += 32) {
        __syncthreads();
        *(u16x8*)&Al[r][hf * 16]     = ra0;
        *(u16x8*)&Al[r][hf * 16 + 8] = ra1;
        *(u16x8*)&Bl[r][hf * 16]     = rb0;
        *(u16x8*)&Bl[r][hf * 16 + 8] = rb1;
        __syncthreads();
        if (k0 + 32 < D_DIM) {
            ra0 = *(const u16x8*)(pa + k0 + 32); ra1 = *(const u16x8*)(pa + k0 + 40);
            rb0 = *(const u16x8*)(pb + k0 + 32); rb1 = *(const u16x8*)(pb + k0 + 40);
        }
        bf16x8 af[4];
#pragma unroll
        for (int mt = 0; mt < 4; ++mt)
            af[mt] = *(const bf16x8*)&Al[wm * 64 + mt * 16 + col16][quad * 8];
#pragma unroll
        for (int nt = 0; nt < 4; ++nt) {
            bf16x8 bfr = *(const bf16x8*)&Bl[wn * 64 + nt * 16 + col16][quad * 8];
#pragma unroll
            for (int mt = 0; mt < 4; ++mt)
                acc[mt][nt] = MFMA16(af[mt], bfr, acc[mt][nt]);
        }
    }
#pragma unroll
    for (int nt = 0; nt < 4; ++nt) {
        int col = bn * 128 + wn * 64 + nt * 16 + col16;
        float bv = bout[col];
#pragma unroll
        for (int mt = 0; mt < 4; ++mt) {
            int row0 = bm * 128 + wm * 64 + mt * 16 + quad * 4;
#pragma unroll
            for (int rr = 0; rr < 4; ++rr) {
                size_t idx = (size_t)(row0 + rr) * D_DIM + col;
                out[idx] = acc[mt][nt][rr] + x[idx] + bv;
            }
        }
    }
}

// ---------------------------------------------------------------------------
extern "C" void kernel_launch(void* const* d_in, const int* in_sizes, int n_in,
                              void* d_out, int out_size, void* d_ws, size_t ws_size,
                              hipStream_t stream) {
    const float* x    = (const float*)d_in[0];
    const float* Wq   = (const float*)d_in[1];
    const float* bq   = (const float*)d_in[2];
    const float* Wv   = (const float*)d_in[3];
    const float* Wout = (const float*)d_in[4];
    const float* bout = (const float*)d_in[5];
    const int*   mask = (const int*)d_in[6];
    float* out = (float*)d_out;

    char* ws = (char*)d_ws;
    u16*   Qbf   = (u16*)(ws);                         // 8 MB
    u16*   QT    = (u16*)(ws + (8u << 20));            // 8 MB
    u16*   attnO = (u16*)(ws + (16u << 20));           // 8 MB
    u16*   W2    = (u16*)(ws + (24u << 20));           // 2 MB
    float* Mbuf  = (float*)(ws + (26u << 20));         // 256 KB
    float* sq05  = (float*)(ws + (26u << 20) + (256u << 10)); // 256 KB

    k_precomp_M<<<dim3(8, 16), dim3(256), 0, stream>>>(Wq, Wv, Mbuf);
    k_precomp_W2<<<dim3(16, 16), dim3(256), 0, stream>>>(Mbuf, Wout, W2);
    k_qproj<<<dim3(32, 8), dim3(256), 0, stream>>>(x, Wq, bq, mask, Qbf, QT, sq05);
    k_flash<<<dim3(512), dim3(256), 0, stream>>>(Qbf, QT, sq05, attnO);
    k_oproj<<<dim3(32, 8), dim3(256), 0, stream>>>(attnO, W2, x, bout, out);
}

// Round 5
// 236.395 us; speedup vs baseline: 1.1411x; 1.1411x over previous
//
#include <hip/hip_runtime.h>

#define S_LEN 2048
#define D_DIM 1024
#define NH    16
#define DHEAD 64

typedef float f32x4 __attribute__((ext_vector_type(4)));
typedef __bf16 bf16x8 __attribute__((ext_vector_type(8)));
typedef unsigned short u16;
typedef unsigned int u32;
typedef unsigned short u16x8 __attribute__((ext_vector_type(8)));
typedef unsigned short u16x4 __attribute__((ext_vector_type(4)));

__device__ __forceinline__ u16 f2bf(float f) {
    union { float f; unsigned u; } c; c.f = f;
    unsigned u = c.u + 0x7fffu + ((c.u >> 16) & 1u);
    return (u16)(u >> 16);
}

#if __has_builtin(__builtin_amdgcn_exp2f)
#define EXP2(x) __builtin_amdgcn_exp2f(x)
#else
#define EXP2(x) exp2f(x)
#endif

// 0.25*log2(e), 0.125*log2(e)
#define C_QK  0.36067376022224085f
#define C_SQ  0.18033688011112043f

#define MFMA16(a, b, c) __builtin_amdgcn_mfma_f32_16x16x32_bf16((a), (b), (c), 0, 0, 0)

// pack two f32 into bf16 pair (truncation; bias cancels in softmax normalize)
__device__ __forceinline__ u32 pack_bf(float lo, float hi) {
    union { float f; u32 u; } a, b; a.f = lo; b.f = hi;
    return (b.u & 0xFFFF0000u) | (a.u >> 16);
}

// ---------------------------------------------------------------------------
// Mpart[z][h*64+j][f] = partial_z sum_e Wq[e, h*64+j] * Wv[e, h*64+f]
// grid (8 jg, 16 h, 4 z): z splits the e-range.
__global__ __launch_bounds__(256) void k_precomp_M(
    const float* __restrict__ Wq, const float* __restrict__ Wv, float* __restrict__ Mpart) {
    __shared__ float red[4][8][64];
    const int tid = threadIdx.x;
    const int f = tid & 63, ks = tid >> 6;
    const int jg = blockIdx.x, h = blockIdx.y, z = blockIdx.z;
    const float* vcol = Wv + h * DHEAD + f;
    const float* qcol = Wq + h * DHEAD + jg * 8;
    float acc[8];
#pragma unroll
    for (int jj = 0; jj < 8; ++jj) acc[jj] = 0.f;
    const int e0 = z * 256 + ks * 64;
    for (int e = e0; e < e0 + 64; ++e) {
        float v = vcol[(size_t)e * D_DIM];
        const float* qr = qcol + (size_t)e * D_DIM;
#pragma unroll
        for (int jj = 0; jj < 8; ++jj) acc[jj] += qr[jj] * v;
    }
#pragma unroll
    for (int jj = 0; jj < 8; ++jj) red[ks][jj][f] = acc[jj];
    __syncthreads();
    for (int t = tid; t < 512; t += 256) {
        int jj = t >> 6, ff = t & 63;
        float s = red[0][jj][ff] + red[1][jj][ff] + red[2][jj][ff] + red[3][jj][ff];
        Mpart[(size_t)z * (NH * 64 * 64) + ((size_t)(h * 64 + jg * 8 + jj)) * 64 + ff] = s * 0.125f;
    }
}

// ---------------------------------------------------------------------------
// W2[o, h*64+j] = sum_f (sum_z Mpart[z,h,j,f]) * Wout[o, h*64+f]   (bf16 out)
__global__ __launch_bounds__(256) void k_precomp_W2(
    const float* __restrict__ Mpart, const float* __restrict__ Wout, u16* __restrict__ W2) {
    __shared__ float Ms[64][65];
    __shared__ float Ws[64][65];
    const int tid = threadIdx.x;
    const int ob = blockIdx.x, h = blockIdx.y;
    {
        int rr = tid >> 2, seg = tid & 3;
        const size_t mo = ((size_t)(h * 64 + rr)) * 64 + seg * 16;
        const float* ws = Wout + (size_t)(ob * 64 + rr) * D_DIM + h * DHEAD + seg * 16;
#pragma unroll
        for (int e = 0; e < 16; ++e) {
            Ms[rr][seg * 16 + e] = Mpart[mo + e] + Mpart[mo + e + 65536]
                                 + Mpart[mo + e + 131072] + Mpart[mo + e + 196608];
            Ws[rr][seg * 16 + e] = ws[e];
        }
    }
    __syncthreads();
    int j = tid & 63, o0 = (tid >> 6) * 16;
    for (int oo = o0; oo < o0 + 16; ++oo) {
        float acc = 0.f;
#pragma unroll
        for (int f = 0; f < 64; ++f) acc += Ms[j][f] * Ws[oo][f];
        W2[(size_t)(ob * 64 + oo) * D_DIM + h * DHEAD + j] = f2bf(acc);
    }
}

// ---------------------------------------------------------------------------
// Q projection (fp32 in, converts in staging) + side-products.
__global__ __launch_bounds__(256) void k_qproj(
    const float* __restrict__ x, const float* __restrict__ Wq,
    const float* __restrict__ bq, const int* __restrict__ mask,
    u16* __restrict__ Qbf, u16* __restrict__ QT, float* __restrict__ sq05) {
    __shared__ u16 Al[128][36];
    __shared__ u16 Bl[128][36];
    const int tid = threadIdx.x, lane = tid & 63, w = tid >> 6;
    const int wm = w & 1, wn = w >> 1;
    const int col16 = lane & 15, quad = lane >> 4;
    const int bm = blockIdx.x, bn = blockIdx.y;

    f32x4 acc[4][4];
    const f32x4 z4 = {0.f, 0.f, 0.f, 0.f};
#pragma unroll
    for (int i = 0; i < 4; ++i)
#pragma unroll
        for (int j = 0; j < 4; ++j) acc[i][j] = z4;

    const int r = tid >> 1, hf = tid & 1;
    const float* pa = x + (size_t)(bm * 128 + r) * D_DIM + hf * 16;
    const float* pb = Wq + (size_t)(bn * 128 + r) * D_DIM + hf * 16;

    f32x4 a0 = *(const f32x4*)(pa),      a1 = *(const f32x4*)(pa + 4);
    f32x4 a2 = *(const f32x4*)(pa + 8),  a3 = *(const f32x4*)(pa + 12);
    f32x4 b0 = *(const f32x4*)(pb),      b1 = *(const f32x4*)(pb + 4);
    f32x4 b2 = *(const f32x4*)(pb + 8),  b3 = *(const f32x4*)(pb + 12);

    for (int k0 = 0; k0 < D_DIM; k0 += 32) {
        u16x8 wa0, wa1, wb0, wb1;
#pragma unroll
        for (int e = 0; e < 4; ++e) {
            wa0[e] = f2bf(a0[e]); wa0[e + 4] = f2bf(a1[e]);
            wa1[e] = f2bf(a2[e]); wa1[e + 4] = f2bf(a3[e]);
            wb0[e] = f2bf(b0[e]); wb0[e + 4] = f2bf(b1[e]);
            wb1[e] = f2bf(b2[e]); wb1[e + 4] = f2bf(b3[e]);
        }
        __syncthreads();
        *(u16x8*)&Al[r][hf * 16]     = wa0;
        *(u16x8*)&Al[r][hf * 16 + 8] = wa1;
        *(u16x8*)&Bl[r][hf * 16]     = wb0;
        *(u16x8*)&Bl[r][hf * 16 + 8] = wb1;
        __syncthreads();
        if (k0 + 32 < D_DIM) {
            a0 = *(const f32x4*)(pa + k0 + 32); a1 = *(const f32x4*)(pa + k0 + 36);
            a2 = *(const f32x4*)(pa + k0 + 40); a3 = *(const f32x4*)(pa + k0 + 44);
            b0 = *(const f32x4*)(pb + k0 + 32); b1 = *(const f32x4*)(pb + k0 + 36);
            b2 = *(const f32x4*)(pb + k0 + 40); b3 = *(const f32x4*)(pb + k0 + 44);
        }
        bf16x8 af[4];
#pragma unroll
        for (int mt = 0; mt < 4; ++mt)
            af[mt] = *(const bf16x8*)&Al[wm * 64 + mt * 16 + col16][quad * 8];
#pragma unroll
        for (int nt = 0; nt < 4; ++nt) {
            bf16x8 bfr = *(const bf16x8*)&Bl[wn * 64 + nt * 16 + col16][quad * 8];
#pragma unroll
            for (int mt = 0; mt < 4; ++mt)
                acc[mt][nt] = MFMA16(af[mt], bfr, acc[mt][nt]);
        }
    }

    const int h = bn * 2 + wn;
    f32x4 ssum[4];
#pragma unroll
    for (int mt = 0; mt < 4; ++mt) ssum[mt] = z4;

#pragma unroll
    for (int nt = 0; nt < 4; ++nt) {
        int col = bn * 128 + wn * 64 + nt * 16 + col16;
        int dloc = nt * 16 + col16;
        float bqv = bq[col];
#pragma unroll
        for (int mt = 0; mt < 4; ++mt) {
            int row0 = bm * 128 + wm * 64 + mt * 16 + quad * 4;
            int b = row0 >> 11, smod0 = row0 & 2047;
            u16x4 pk;
#pragma unroll
            for (int rr = 0; rr < 4; ++rr) {
                float qv = acc[mt][nt][rr] + bqv;
                ssum[mt][rr] += qv * qv;
                u16 bv = f2bf(qv);
                pk[rr] = bv;
                Qbf[(size_t)(row0 + rr) * D_DIM + col] = bv;
            }
            *(u16x4*)(QT + ((size_t)(b * NH + h) * DHEAD + dloc) * S_LEN + smod0) = pk;
        }
    }
#pragma unroll
    for (int mt = 0; mt < 4; ++mt) {
        int row0 = bm * 128 + wm * 64 + mt * 16 + quad * 4;
        int b = row0 >> 11, smod0 = row0 & 2047;
#pragma unroll
        for (int rr = 0; rr < 4; ++rr) {
            float v = ssum[mt][rr];
            v += __shfl_xor(v, 1); v += __shfl_xor(v, 2);
            v += __shfl_xor(v, 4); v += __shfl_xor(v, 8);
            if (col16 == 0) {
                int sidx = smod0 + rr;
                float out = mask[b * S_LEN + sidx] ? v * C_SQ : 1e30f;
                sq05[((size_t)(b * NH + h)) * S_LEN + sidx] = out;
            }
        }
    }
}

// ---------------------------------------------------------------------------
// Fused L2 attention, transpose-free, kt-split to avoid register spill.
// Block = (b,h,qt128), 4 waves: wq = q-half (64 q), wk = key-half (64 keys).
__global__ __launch_bounds__(256, 2) void k_flash(
    const u16* __restrict__ Qbf, const u16* __restrict__ QT,
    const float* __restrict__ sq05, u16* __restrict__ attnO) {
    __shared__ __align__(16) char smem[34816];
    u16* Kt  = (u16*)smem;              // [128][64] u16, xor-swizzled cols
    u16* KtT = (u16*)(smem + 16384);    // [64][128] u16, xor-swizzled cols
    float* sql = (float*)(smem + 32768);// [128]

    const int tid = threadIdx.x, lane = tid & 63, w = tid >> 6;
    const int col16 = lane & 15, quad = lane >> 4;
    const int wq = w & 1, wk = w >> 1;
    const int qt = blockIdx.x & 15;
    const int h = (blockIdx.x >> 4) & 15;
    const int b = blockIdx.x >> 8;
    const u16* qbase = Qbf + (size_t)b * S_LEN * D_DIM + h * DHEAD;
    const u16* qtbase = QT + ((size_t)(b * NH + h)) * DHEAD * S_LEN;
    const float* sqb = sq05 + ((size_t)(b * NH + h)) * S_LEN;

    // loop-invariant Q^T B-fragments (global, once)
    bf16x8 qb[4][2];
#pragma unroll
    for (int nq = 0; nq < 4; ++nq)
#pragma unroll
        for (int k0 = 0; k0 < 2; ++k0)
            qb[nq][k0] = *(const bf16x8*)(qbase +
                (size_t)(qt * 128 + wq * 64 + nq * 16 + col16) * D_DIM + k0 * 32 + quad * 8);

    // Kt read offset closed form: krow(kt,kbh) = krow00 + kt*2048 + kbh*256
    const int r00 = wk * 64 + (col16 >> 2) * 8 + (col16 & 3);
    const int swzA = (col16 & 3) | (((col16 >> 2) & 1) << 2);
    const int krow00 = r00 * 64 + (quad ^ swzA) * 8;
    const int sq00 = wk * 64 + quad * 8;
    // KtT read offsets per dblk (kt handled by ^32)
    int vrow[4];
#pragma unroll
    for (int dblk = 0; dblk < 4; ++dblk) {
        int rT = dblk * 16 + col16;
        vrow[dblk] = rT * 128 + ((wk * 8 + quad) ^ (rT & 7)) * 8;
    }

    // staging assignments
    const int kr = tid >> 1, ks = tid & 1;
    const int td = tid >> 2, ts = tid & 3;
    const int kswz = (kr & 3) | (((kr >> 3) & 1) << 2);
    const int tswz = td & 7;
    const u16* ksrc = qbase + (size_t)kr * D_DIM + ks * 32;
    const u16* tsrc = qtbase + (size_t)td * S_LEN + ts * 32;

    u16x8 pk[4], pt[4];
    float sv = 0.f;
#pragma unroll
    for (int i = 0; i < 4; ++i) pk[i] = *(const u16x8*)(ksrc + i * 8);
#pragma unroll
    for (int i = 0; i < 4; ++i) pt[i] = *(const u16x8*)(tsrc + i * 8);
    if (tid < 128) sv = sqb[tid];

    f32x4 Oacc[4][4];
    float lsum[4];
    const f32x4 z4 = {0.f, 0.f, 0.f, 0.f};
#pragma unroll
    for (int d = 0; d < 4; ++d) {
        lsum[d] = 0.f;
#pragma unroll
        for (int n = 0; n < 4; ++n) Oacc[d][n] = z4;
    }

    for (int j = 0; j < S_LEN / 128; ++j) {
        __syncthreads();
#pragma unroll
        for (int i = 0; i < 4; ++i)
            *(u16x8*)(Kt + kr * 64 + ((ks * 4 + i) ^ kswz) * 8) = pk[i];
#pragma unroll
        for (int i = 0; i < 4; ++i)
            *(u16x8*)(KtT + td * 128 + ((ts * 4 + i) ^ tswz) * 8) = pt[i];
        if (tid < 128) sql[tid] = sv;
        __syncthreads();

        int jn = (j + 1) & 15;
        {
            const u16* kn = ksrc + (size_t)jn * 128 * D_DIM;
            const u16* tn = tsrc + (size_t)jn * 128;
#pragma unroll
            for (int i = 0; i < 4; ++i) pk[i] = *(const u16x8*)(kn + i * 8);
#pragma unroll
            for (int i = 0; i < 4; ++i) pt[i] = *(const u16x8*)(tn + i * 8);
            if (tid < 128) sv = sqb[jn * 128 + tid];
        }

        // two key-half rounds: S^T (32 keys x 64 q) -> exp/pack -> PV
        for (int kt = 0; kt < 2; ++kt) {
            f32x4 sacc[2][4];
#pragma unroll
            for (int kbh = 0; kbh < 2; ++kbh)
#pragma unroll
                for (int nq = 0; nq < 4; ++nq) sacc[kbh][nq] = z4;
#pragma unroll
            for (int kbh = 0; kbh < 2; ++kbh) {
                int kro = krow00 + kt * 2048 + kbh * 256;
                bf16x8 a0 = *(const bf16x8*)(Kt + kro);
                bf16x8 a1 = *(const bf16x8*)(Kt + (kro ^ 32));
#pragma unroll
                for (int nq = 0; nq < 4; ++nq) {
                    sacc[kbh][nq] = MFMA16(a0, qb[nq][0], sacc[kbh][nq]);
                    sacc[kbh][nq] = MFMA16(a1, qb[nq][1], sacc[kbh][nq]);
                }
            }

            u32 pf[4][4];
#pragma unroll
            for (int kbh = 0; kbh < 2; ++kbh) {
                f32x4 sqv = *(const f32x4*)(sql + sq00 + kt * 32 + kbh * 4);
#pragma unroll
                for (int nq = 0; nq < 4; ++nq) {
                    float p0 = EXP2(fmaf(sacc[kbh][nq][0], C_QK, -sqv[0]));
                    float p1 = EXP2(fmaf(sacc[kbh][nq][1], C_QK, -sqv[1]));
                    float p2 = EXP2(fmaf(sacc[kbh][nq][2], C_QK, -sqv[2]));
                    float p3 = EXP2(fmaf(sacc[kbh][nq][3], C_QK, -sqv[3]));
                    lsum[nq] += (p0 + p1) + (p2 + p3);
                    pf[nq][kbh * 2]     = pack_bf(p0, p1);
                    pf[nq][kbh * 2 + 1] = pack_bf(p2, p3);
                }
            }

            bf16x8 va[4];
#pragma unroll
            for (int dblk = 0; dblk < 4; ++dblk)
                va[dblk] = *(const bf16x8*)(KtT + (vrow[dblk] ^ (kt * 32)));
#pragma unroll
            for (int nq = 0; nq < 4; ++nq) {
                union { u32 u[4]; bf16x8 b; } pb;
#pragma unroll
                for (int i = 0; i < 4; ++i) pb.u[i] = pf[nq][i];
#pragma unroll
                for (int dblk = 0; dblk < 4; ++dblk)
                    Oacc[dblk][nq] = MFMA16(va[dblk], pb.b, Oacc[dblk][nq]);
            }
        }
    }

    // reduce lsum across quads (lane bits 4,5): each lane then has the
    // full 64-key (this wave's half) sum for q = col16
#pragma unroll
    for (int nq = 0; nq < 4; ++nq) {
        float v = lsum[nq];
        v += __shfl_xor(v, 16);
        v += __shfl_xor(v, 32);
        lsum[nq] = v;
    }

    // cross-wave (key-half) combine + epilogue
    __syncthreads();
    float* Obuf = (float*)smem;                 // [2][16][64] f32x4
    float* lred = (float*)(smem + 32768);       // [2][4][64]
    if (wk == 1) {
#pragma unroll
        for (int dblk = 0; dblk < 4; ++dblk)
#pragma unroll
            for (int nq = 0; nq < 4; ++nq)
                *(f32x4*)(Obuf + ((wq * 16 + dblk * 4 + nq) * 64 + lane) * 4) = Oacc[dblk][nq];
#pragma unroll
        for (int nq = 0; nq < 4; ++nq)
            lred[(wq * 4 + nq) * 64 + lane] = lsum[nq];
    }
    __syncthreads();
    if (wk == 0) {
        float rinv[4];
#pragma unroll
        for (int nq = 0; nq < 4; ++nq)
            rinv[nq] = 1.f / (lsum[nq] + lred[(wq * 4 + nq) * 64 + lane]);
        u16* obase = attnO + (size_t)b * S_LEN * D_DIM + h * DHEAD;
#pragma unroll
        for (int dblk = 0; dblk < 4; ++dblk)
#pragma unroll
            for (int nq = 0; nq < 4; ++nq) {
                f32x4 o = Oacc[dblk][nq] + *(const f32x4*)(Obuf + ((wq * 16 + dblk * 4 + nq) * 64 + lane) * 4);
                int q = qt * 128 + wq * 64 + nq * 16 + col16;
                u16x4 pkk;
#pragma unroll
                for (int rr = 0; rr < 4; ++rr) pkk[rr] = f2bf(o[rr] * rinv[nq]);
                *(u16x4*)(obase + (size_t)q * D_DIM + dblk * 16 + quad * 4) = pkk;
            }
    }
}

// ---------------------------------------------------------------------------
// Output GEMM: out[s,o] = x[s,o] + bout[o] + sum_c attnO[s,c] * W2[o,c]
__global__ __launch_bounds__(256) void k_oproj(
    const u16* __restrict__ attnO, const u16* __restrict__ W2,
    const float* __restrict__ x, const float* __restrict__ bout, float* __restrict__ out) {
    __shared__ u16 Al[128][36];
    __shared__ u16 Bl[128][36];
    const int tid = threadIdx.x, lane = tid & 63, w = tid >> 6;
    const int wm = w & 1, wn = w >> 1;
    const int col16 = lane & 15, quad = lane >> 4;
    const int bm = blockIdx.x, bn = blockIdx.y;

    f32x4 acc[4][4];
    const f32x4 z4 = {0.f, 0.f, 0.f, 0.f};
#pragma unroll
    for (int i = 0; i < 4; ++i)
#pragma unroll
        for (int j = 0; j < 4; ++j) acc[i][j] = z4;

    const int r = tid >> 1, hf = tid & 1;
    const u16* pa = attnO + (size_t)(bm * 128 + r) * D_DIM + hf * 16;
    const u16* pb = W2 + (size_t)(bn * 128 + r) * D_DIM + hf * 16;

    u16x8 ra0 = *(const u16x8*)(pa),     ra1 = *(const u16x8*)(pa + 8);
    u16x8 rb0 = *(const u16x8*)(pb),     rb1 = *(const u16x8*)(pb + 8);

    for (int k0 = 0; k0 < D_DIM; k0 += 32) {
        __syncthreads();
        *(u16x8*)&Al[r][hf * 16]     = ra0;
        *(u16x8*)&Al[r][hf * 16 + 8] = ra1;
        *(u16x8*)&Bl[r][hf * 16]     = rb0;
        *(u16x8*)&Bl[r][hf * 16 + 8] = rb1;
        __syncthreads();
        if (k0 + 32 < D_DIM) {
            ra0 = *(const u16x8*)(pa + k0 + 32); ra1 = *(const u16x8*)(pa + k0 + 40);
            rb0 = *(const u16x8*)(pb + k0 + 32); rb1 = *(const u16x8*)(pb + k0 + 40);
        }
        bf16x8 af[4];
#pragma unroll
        for (int mt = 0; mt < 4; ++mt)
            af[mt] = *(const bf16x8*)&Al[wm * 64 + mt * 16 + col16][quad * 8];
#pragma unroll
        for (int nt = 0; nt < 4; ++nt) {
            bf16x8 bfr = *(const bf16x8*)&Bl[wn * 64 + nt * 16 + col16][quad * 8];
#pragma unroll
            for (int mt = 0; mt < 4; ++mt)
                acc[mt][nt] = MFMA16(af[mt], bfr, acc[mt][nt]);
        }
    }
#pragma unroll
    for (int nt = 0; nt < 4; ++nt) {
        int col = bn * 128 + wn * 64 + nt * 16 + col16;
        float bv = bout[col];
#pragma unroll
        for (int mt = 0; mt < 4; ++mt) {
            int row0 = bm * 128 + wm * 64 + mt * 16 + quad * 4;
#pragma unroll
            for (int rr = 0; rr < 4; ++rr) {
                size_t idx = (size_t)(row0 + rr) * D_DIM + col;
                out[idx] = acc[mt][nt][rr] + x[idx] + bv;
            }
        }
    }
}

// ---------------------------------------------------------------------------
extern "C" void kernel_launch(void* const* d_in, const int* in_sizes, int n_in,
                              void* d_out, int out_size, void* d_ws, size_t ws_size,
                              hipStream_t stream) {
    const float* x    = (const float*)d_in[0];
    const float* Wq   = (const float*)d_in[1];
    const float* bq   = (const float*)d_in[2];
    const float* Wv   = (const float*)d_in[3];
    const float* Wout = (const float*)d_in[4];
    const float* bout = (const float*)d_in[5];
    const int*   mask = (const int*)d_in[6];
    float* out = (float*)d_out;

    char* ws = (char*)d_ws;
    u16*   Qbf   = (u16*)(ws);                         // 8 MB
    u16*   QT    = (u16*)(ws + (8u << 20));            // 8 MB
    u16*   attnO = (u16*)(ws + (16u << 20));           // 8 MB
    u16*   W2    = (u16*)(ws + (24u << 20));           // 2 MB
    float* Mpart = (float*)(ws + (26u << 20));         // 1 MB (4 partials)
    float* sq05  = (float*)(ws + (27u << 20));         // 256 KB

    k_precomp_M<<<dim3(8, 16, 4), dim3(256), 0, stream>>>(Wq, Wv, Mpart);
    k_precomp_W2<<<dim3(16, 16), dim3(256), 0, stream>>>(Mpart, Wout, W2);
    k_qproj<<<dim3(32, 8), dim3(256), 0, stream>>>(x, Wq, bq, mask, Qbf, QT, sq05);
    k_flash<<<dim3(512), dim3(256), 0, stream>>>(Qbf, QT, sq05, attnO);
    k_oproj<<<dim3(32, 8), dim3(256), 0, stream>>>(attnO, W2, x, bout, out);
}

// Round 6
// 225.714 us; speedup vs baseline: 1.1951x; 1.0473x over previous
//
#include <hip/hip_runtime.h>

#define S_LEN 2048
#define D_DIM 1024
#define NH    16
#define DHEAD 64

typedef float f32x4 __attribute__((ext_vector_type(4)));
typedef __bf16 bf16x8 __attribute__((ext_vector_type(8)));
typedef unsigned short u16;
typedef unsigned int u32;
typedef unsigned short u16x8 __attribute__((ext_vector_type(8)));
typedef unsigned short u16x4 __attribute__((ext_vector_type(4)));

__device__ __forceinline__ u16 f2bf(float f) {
    union { float f; unsigned u; } c; c.f = f;
    unsigned u = c.u + 0x7fffu + ((c.u >> 16) & 1u);
    return (u16)(u >> 16);
}

#if __has_builtin(__builtin_amdgcn_exp2f)
#define EXP2(x) __builtin_amdgcn_exp2f(x)
#else
#define EXP2(x) exp2f(x)
#endif

// 0.25*log2(e), 0.125*log2(e)
#define C_QK  0.36067376022224085f
#define C_SQ  0.18033688011112043f

#define MFMA16(a, b, c) __builtin_amdgcn_mfma_f32_16x16x32_bf16((a), (b), (c), 0, 0, 0)

// pack two f32 into bf16 pair (truncation; bias cancels in softmax normalize)
__device__ __forceinline__ u32 pack_bf(float lo, float hi) {
    union { float f; u32 u; } a, b; a.f = lo; b.f = hi;
    return (b.u & 0xFFFF0000u) | (a.u >> 16);
}

// ---------------------------------------------------------------------------
// Convert x (4.19M) and Wq (1.05M) fp32 -> bf16 once. 8 elems/thread.
__global__ __launch_bounds__(256) void k_cvt(
    const float* __restrict__ x, const float* __restrict__ wq,
    u16* __restrict__ xb, u16* __restrict__ wqb) {
    const int bid = blockIdx.x;
    const float* s; u16* d; size_t base;
    if (bid < 2048) { s = x;  d = xb;  base = (size_t)bid * 2048 + threadIdx.x * 8; }
    else           { s = wq; d = wqb; base = (size_t)(bid - 2048) * 2048 + threadIdx.x * 8; }
    f32x4 a = *(const f32x4*)(s + base);
    f32x4 b = *(const f32x4*)(s + base + 4);
    u16x8 o;
#pragma unroll
    for (int e = 0; e < 4; ++e) { o[e] = f2bf(a[e]); o[e + 4] = f2bf(b[e]); }
    *(u16x8*)(d + base) = o;
}

// ---------------------------------------------------------------------------
// Mpart[z][h*64+j][f] = partial_z sum_e Wq[e, h*64+j] * Wv[e, h*64+f]
__global__ __launch_bounds__(256) void k_precomp_M(
    const float* __restrict__ Wq, const float* __restrict__ Wv, float* __restrict__ Mpart) {
    __shared__ float red[4][8][64];
    const int tid = threadIdx.x;
    const int f = tid & 63, ks = tid >> 6;
    const int jg = blockIdx.x, h = blockIdx.y, z = blockIdx.z;
    const float* vcol = Wv + h * DHEAD + f;
    const float* qcol = Wq + h * DHEAD + jg * 8;
    float acc[8];
#pragma unroll
    for (int jj = 0; jj < 8; ++jj) acc[jj] = 0.f;
    const int e0 = z * 256 + ks * 64;
    for (int e = e0; e < e0 + 64; ++e) {
        float v = vcol[(size_t)e * D_DIM];
        const float* qr = qcol + (size_t)e * D_DIM;
#pragma unroll
        for (int jj = 0; jj < 8; ++jj) acc[jj] += qr[jj] * v;
    }
#pragma unroll
    for (int jj = 0; jj < 8; ++jj) red[ks][jj][f] = acc[jj];
    __syncthreads();
    for (int t = tid; t < 512; t += 256) {
        int jj = t >> 6, ff = t & 63;
        float s = red[0][jj][ff] + red[1][jj][ff] + red[2][jj][ff] + red[3][jj][ff];
        Mpart[(size_t)z * (NH * 64 * 64) + ((size_t)(h * 64 + jg * 8 + jj)) * 64 + ff] = s * 0.125f;
    }
}

// ---------------------------------------------------------------------------
// W2[o, h*64+j] = sum_f (sum_z Mpart[z,h,j,f]) * Wout[o, h*64+f]   (bf16 out)
__global__ __launch_bounds__(256) void k_precomp_W2(
    const float* __restrict__ Mpart, const float* __restrict__ Wout, u16* __restrict__ W2) {
    __shared__ float Ms[64][65];
    __shared__ float Ws[64][65];
    const int tid = threadIdx.x;
    const int ob = blockIdx.x, h = blockIdx.y;
    {
        int rr = tid >> 2, seg = tid & 3;
        const size_t mo = ((size_t)(h * 64 + rr)) * 64 + seg * 16;
        const float* ws = Wout + (size_t)(ob * 64 + rr) * D_DIM + h * DHEAD + seg * 16;
#pragma unroll
        for (int e = 0; e < 16; ++e) {
            Ms[rr][seg * 16 + e] = Mpart[mo + e] + Mpart[mo + e + 65536]
                                 + Mpart[mo + e + 131072] + Mpart[mo + e + 196608];
            Ws[rr][seg * 16 + e] = ws[e];
        }
    }
    __syncthreads();
    int j = tid & 63, o0 = (tid >> 6) * 16;
    for (int oo = o0; oo < o0 + 16; ++oo) {
        float acc = 0.f;
#pragma unroll
        for (int f = 0; f < 64; ++f) acc += Ms[j][f] * Ws[oo][f];
        W2[(size_t)(ob * 64 + oo) * D_DIM + h * DHEAD + j] = f2bf(acc);
    }
}

// ---------------------------------------------------------------------------
// Q projection, pure bf16, 128x64 tile (bn = head), BK=64, 512 blocks.
__global__ __launch_bounds__(256) void k_qproj(
    const u16* __restrict__ xb, const u16* __restrict__ wqb,
    const float* __restrict__ bq, const int* __restrict__ mask,
    u16* __restrict__ Qbf, u16* __restrict__ QT, float* __restrict__ sq05) {
    __shared__ u16 Al[128][72];
    __shared__ u16 Bl[64][72];
    __shared__ float sqred[128];
    const int tid = threadIdx.x, lane = tid & 63, w = tid >> 6;
    const int wm = w & 1, wn = w >> 1;
    const int col16 = lane & 15, quad = lane >> 4;
    const int bm = blockIdx.x, bn = blockIdx.y;   // bn = head

    f32x4 acc[4][2];
    const f32x4 z4 = {0.f, 0.f, 0.f, 0.f};
#pragma unroll
    for (int i = 0; i < 4; ++i)
#pragma unroll
        for (int j = 0; j < 2; ++j) acc[i][j] = z4;

    const int ar = tid >> 1, ah = tid & 1;
    const int br = tid >> 2, bs = tid & 3;
    const u16* pa = xb + (size_t)(bm * 128 + ar) * D_DIM + ah * 32;
    const u16* pb = wqb + (size_t)(bn * 64 + br) * D_DIM + bs * 16;

    u16x8 ra[4], rb[2];
#pragma unroll
    for (int i = 0; i < 4; ++i) ra[i] = *(const u16x8*)(pa + i * 8);
#pragma unroll
    for (int i = 0; i < 2; ++i) rb[i] = *(const u16x8*)(pb + i * 8);

    for (int k0 = 0; k0 < D_DIM; k0 += 64) {
        __syncthreads();
#pragma unroll
        for (int i = 0; i < 4; ++i) *(u16x8*)&Al[ar][ah * 32 + i * 8] = ra[i];
#pragma unroll
        for (int i = 0; i < 2; ++i) *(u16x8*)&Bl[br][bs * 16 + i * 8] = rb[i];
        __syncthreads();
        if (k0 + 64 < D_DIM) {
#pragma unroll
            for (int i = 0; i < 4; ++i) ra[i] = *(const u16x8*)(pa + k0 + 64 + i * 8);
#pragma unroll
            for (int i = 0; i < 2; ++i) rb[i] = *(const u16x8*)(pb + k0 + 64 + i * 8);
        }
#pragma unroll
        for (int kh = 0; kh < 2; ++kh) {
            bf16x8 af[4];
#pragma unroll
            for (int mt = 0; mt < 4; ++mt)
                af[mt] = *(const bf16x8*)&Al[wm * 64 + mt * 16 + col16][kh * 32 + quad * 8];
#pragma unroll
            for (int nt = 0; nt < 2; ++nt) {
                bf16x8 bfr = *(const bf16x8*)&Bl[wn * 32 + nt * 16 + col16][kh * 32 + quad * 8];
#pragma unroll
                for (int mt = 0; mt < 4; ++mt)
                    acc[mt][nt] = MFMA16(af[mt], bfr, acc[mt][nt]);
            }
        }
    }

    const int h = bn;
    f32x4 ssum[4];
#pragma unroll
    for (int mt = 0; mt < 4; ++mt) ssum[mt] = z4;

#pragma unroll
    for (int nt = 0; nt < 2; ++nt) {
        int dloc = wn * 32 + nt * 16 + col16;
        int col = bn * 64 + dloc;
        float bqv = bq[col];
#pragma unroll
        for (int mt = 0; mt < 4; ++mt) {
            int row0 = bm * 128 + wm * 64 + mt * 16 + quad * 4;
            int b = row0 >> 11, smod0 = row0 & 2047;
            u16x4 pk;
#pragma unroll
            for (int rr = 0; rr < 4; ++rr) {
                float qv = acc[mt][nt][rr] + bqv;
                ssum[mt][rr] += qv * qv;
                u16 bv = f2bf(qv);
                pk[rr] = bv;
                Qbf[(size_t)(row0 + rr) * D_DIM + col] = bv;
            }
            *(u16x4*)(QT + ((size_t)(b * NH + h) * DHEAD + dloc) * S_LEN + smod0) = pk;
        }
    }
    // ||q||^2: reduce 16 lanes (this wave's 32 cols), then combine wn halves
    float vred[4][4];
#pragma unroll
    for (int mt = 0; mt < 4; ++mt)
#pragma unroll
        for (int rr = 0; rr < 4; ++rr) {
            float v = ssum[mt][rr];
            v += __shfl_xor(v, 1); v += __shfl_xor(v, 2);
            v += __shfl_xor(v, 4); v += __shfl_xor(v, 8);
            vred[mt][rr] = v;
        }
    if (wn == 1 && col16 == 0) {
#pragma unroll
        for (int mt = 0; mt < 4; ++mt)
#pragma unroll
            for (int rr = 0; rr < 4; ++rr)
                sqred[wm * 64 + mt * 16 + quad * 4 + rr] = vred[mt][rr];
    }
    __syncthreads();
    if (wn == 0 && col16 == 0) {
#pragma unroll
        for (int mt = 0; mt < 4; ++mt)
#pragma unroll
            for (int rr = 0; rr < 4; ++rr) {
                int rloc = wm * 64 + mt * 16 + quad * 4 + rr;
                int row0 = bm * 128 + rloc;
                int b = row0 >> 11, sidx = row0 & 2047;
                float v = vred[mt][rr] + sqred[rloc];
                float o = mask[b * S_LEN + sidx] ? v * C_SQ : 1e30f;
                sq05[((size_t)(b * NH + h)) * S_LEN + sidx] = o;
            }
    }
}

// ---------------------------------------------------------------------------
// Fused L2 attention, transpose-free. Block = (b,h,qt64), grid 1024.
// 4 waves: wq = q-half (32 q), wk = key-half (64 of each 128-key tile).
__global__ __launch_bounds__(256, 3) void k_flash(
    const u16* __restrict__ Qbf, const u16* __restrict__ QT,
    const float* __restrict__ sq05, u16* __restrict__ attnO) {
    __shared__ __align__(16) char smem[34816];
    u16* Kt  = (u16*)smem;              // [128][64] u16, xor-swizzled cols
    u16* KtT = (u16*)(smem + 16384);    // [64][128] u16, xor-swizzled cols
    float* sql = (float*)(smem + 32768);// [128]

    const int tid = threadIdx.x, lane = tid & 63, w = tid >> 6;
    const int col16 = lane & 15, quad = lane >> 4;
    const int wq = w & 1, wk = w >> 1;
    const int qt = blockIdx.x & 31;
    const int h = (blockIdx.x >> 5) & 15;
    const int b = blockIdx.x >> 9;
    const u16* qbase = Qbf + (size_t)b * S_LEN * D_DIM + h * DHEAD;
    const u16* qtbase = QT + ((size_t)(b * NH + h)) * DHEAD * S_LEN;
    const float* sqb = sq05 + ((size_t)(b * NH + h)) * S_LEN;

    // loop-invariant Q^T B-fragments (global, once)
    bf16x8 qb[2][2];
#pragma unroll
    for (int nq = 0; nq < 2; ++nq)
#pragma unroll
        for (int k0 = 0; k0 < 2; ++k0)
            qb[nq][k0] = *(const bf16x8*)(qbase +
                (size_t)(qt * 64 + wq * 32 + nq * 16 + col16) * D_DIM + k0 * 32 + quad * 8);

    // Kt read offset closed form: krow(kt,kbh) = krow00 + kt*2048 + kbh*256
    const int r00 = wk * 64 + (col16 >> 2) * 8 + (col16 & 3);
    const int swzA = (col16 & 3) | (((col16 >> 2) & 1) << 2);
    const int krow00 = r00 * 64 + (quad ^ swzA) * 8;
    const int sq00 = wk * 64 + quad * 8;
    // KtT read offsets per dblk (kt handled by ^32)
    int vrow[4];
#pragma unroll
    for (int dblk = 0; dblk < 4; ++dblk) {
        int rT = dblk * 16 + col16;
        vrow[dblk] = rT * 128 + ((wk * 8 + quad) ^ (rT & 7)) * 8;
    }

    // staging assignments
    const int kr = tid >> 1, ks = tid & 1;
    const int td = tid >> 2, ts = tid & 3;
    const int kswz = (kr & 3) | (((kr >> 3) & 1) << 2);
    const int tswz = td & 7;
    const u16* ksrc = qbase + (size_t)kr * D_DIM + ks * 32;
    const u16* tsrc = qtbase + (size_t)td * S_LEN + ts * 32;

    u16x8 pk[4], pt[4];
    float sv = 0.f;
#pragma unroll
    for (int i = 0; i < 4; ++i) pk[i] = *(const u16x8*)(ksrc + i * 8);
#pragma unroll
    for (int i = 0; i < 4; ++i) pt[i] = *(const u16x8*)(tsrc + i * 8);
    if (tid < 128) sv = sqb[tid];

    f32x4 Oacc[4][2];
    float lsum[2];
    const f32x4 z4 = {0.f, 0.f, 0.f, 0.f};
#pragma unroll
    for (int n = 0; n < 2; ++n) {
        lsum[n] = 0.f;
#pragma unroll
        for (int d = 0; d < 4; ++d) Oacc[d][n] = z4;
    }

    for (int j = 0; j < S_LEN / 128; ++j) {
        __syncthreads();
#pragma unroll
        for (int i = 0; i < 4; ++i)
            *(u16x8*)(Kt + kr * 64 + ((ks * 4 + i) ^ kswz) * 8) = pk[i];
#pragma unroll
        for (int i = 0; i < 4; ++i)
            *(u16x8*)(KtT + td * 128 + ((ts * 4 + i) ^ tswz) * 8) = pt[i];
        if (tid < 128) sql[tid] = sv;
        __syncthreads();

        int jn = (j + 1) & 15;
        {
            const u16* kn = ksrc + (size_t)jn * 128 * D_DIM;
            const u16* tn = tsrc + (size_t)jn * 128;
#pragma unroll
            for (int i = 0; i < 4; ++i) pk[i] = *(const u16x8*)(kn + i * 8);
#pragma unroll
            for (int i = 0; i < 4; ++i) pt[i] = *(const u16x8*)(tn + i * 8);
            if (tid < 128) sv = sqb[jn * 128 + tid];
        }

#pragma unroll
        for (int kt = 0; kt < 2; ++kt) {
            f32x4 sacc[2][2];
#pragma unroll
            for (int kbh = 0; kbh < 2; ++kbh)
#pragma unroll
                for (int nq = 0; nq < 2; ++nq) sacc[kbh][nq] = z4;
#pragma unroll
            for (int kbh = 0; kbh < 2; ++kbh) {
                int kro = krow00 + kt * 2048 + kbh * 256;
                bf16x8 a0 = *(const bf16x8*)(Kt + kro);
                bf16x8 a1 = *(const bf16x8*)(Kt + (kro ^ 32));
#pragma unroll
                for (int nq = 0; nq < 2; ++nq) {
                    sacc[kbh][nq] = MFMA16(a0, qb[nq][0], sacc[kbh][nq]);
                    sacc[kbh][nq] = MFMA16(a1, qb[nq][1], sacc[kbh][nq]);
                }
            }

            u32 pf[2][4];
#pragma unroll
            for (int kbh = 0; kbh < 2; ++kbh) {
                f32x4 sqv = *(const f32x4*)(sql + sq00 + kt * 32 + kbh * 4);
#pragma unroll
                for (int nq = 0; nq < 2; ++nq) {
                    float p0 = EXP2(fmaf(sacc[kbh][nq][0], C_QK, -sqv[0]));
                    float p1 = EXP2(fmaf(sacc[kbh][nq][1], C_QK, -sqv[1]));
                    float p2 = EXP2(fmaf(sacc[kbh][nq][2], C_QK, -sqv[2]));
                    float p3 = EXP2(fmaf(sacc[kbh][nq][3], C_QK, -sqv[3]));
                    lsum[nq] += (p0 + p1) + (p2 + p3);
                    pf[nq][kbh * 2]     = pack_bf(p0, p1);
                    pf[nq][kbh * 2 + 1] = pack_bf(p2, p3);
                }
            }

            bf16x8 va[4];
#pragma unroll
            for (int dblk = 0; dblk < 4; ++dblk)
                va[dblk] = *(const bf16x8*)(KtT + (vrow[dblk] ^ (kt * 32)));
#pragma unroll
            for (int nq = 0; nq < 2; ++nq) {
                union { u32 u[4]; bf16x8 b; } pb;
#pragma unroll
                for (int i = 0; i < 4; ++i) pb.u[i] = pf[nq][i];
#pragma unroll
                for (int dblk = 0; dblk < 4; ++dblk)
                    Oacc[dblk][nq] = MFMA16(va[dblk], pb.b, Oacc[dblk][nq]);
            }
        }
    }

    // reduce lsum across quads: each lane then has this wave's 64-key sum
#pragma unroll
    for (int nq = 0; nq < 2; ++nq) {
        float v = lsum[nq];
        v += __shfl_xor(v, 16);
        v += __shfl_xor(v, 32);
        lsum[nq] = v;
    }

    // cross-wave (key-half) combine + epilogue
    __syncthreads();
    float* Obuf = (float*)smem;                 // [2][8][64] f32x4 = 16 KB
    float* lred = (float*)(smem + 16384);       // [2][2][64]
    if (wk == 1) {
#pragma unroll
        for (int dblk = 0; dblk < 4; ++dblk)
#pragma unroll
            for (int nq = 0; nq < 2; ++nq)
                *(f32x4*)(Obuf + ((wq * 8 + dblk * 2 + nq) * 64 + lane) * 4) = Oacc[dblk][nq];
#pragma unroll
        for (int nq = 0; nq < 2; ++nq)
            lred[(wq * 2 + nq) * 64 + lane] = lsum[nq];
    }
    __syncthreads();
    if (wk == 0) {
        float rinv[2];
#pragma unroll
        for (int nq = 0; nq < 2; ++nq)
            rinv[nq] = 1.f / (lsum[nq] + lred[(wq * 2 + nq) * 64 + lane]);
        u16* obase = attnO + (size_t)b * S_LEN * D_DIM + h * DHEAD;
#pragma unroll
        for (int dblk = 0; dblk < 4; ++dblk)
#pragma unroll
            for (int nq = 0; nq < 2; ++nq) {
                f32x4 o = Oacc[dblk][nq] + *(const f32x4*)(Obuf + ((wq * 8 + dblk * 2 + nq) * 64 + lane) * 4);
                int q = qt * 64 + wq * 32 + nq * 16 + col16;
                u16x4 pkk;
#pragma unroll
                for (int rr = 0; rr < 4; ++rr) pkk[rr] = f2bf(o[rr] * rinv[nq]);
                *(u16x4*)(obase + (size_t)q * D_DIM + dblk * 16 + quad * 4) = pkk;
            }
    }
}

// ---------------------------------------------------------------------------
// Output GEMM, 128x64 tile, 512 blocks: out[s,o] = x[s,o]+bout[o]+attnO·W2^T
__global__ __launch_bounds__(256) void k_oproj(
    const u16* __restrict__ attnO, const u16* __restrict__ W2,
    const float* __restrict__ x, const float* __restrict__ bout, float* __restrict__ out) {
    __shared__ u16 Al[128][72];
    __shared__ u16 Bl[64][72];
    const int tid = threadIdx.x, lane = tid & 63, w = tid >> 6;
    const int wm = w & 1, wn = w >> 1;
    const int col16 = lane & 15, quad = lane >> 4;
    const int bm = blockIdx.x, bn = blockIdx.y;

    f32x4 acc[4][2];
    const f32x4 z4 = {0.f, 0.f, 0.f, 0.f};
#pragma unroll
    for (int i = 0; i < 4; ++i)
#pragma unroll
        for (int j = 0; j < 2; ++j) acc[i][j] = z4;

    const int ar = tid >> 1, ah = tid & 1;
    const int br = tid >> 2, bs = tid & 3;
    const u16* pa = attnO + (size_t)(bm * 128 + ar) * D_DIM + ah * 32;
    const u16* pb = W2 + (size_t)(bn * 64 + br) * D_DIM + bs * 16;

    u16x8 ra[4], rb[2];
#pragma unroll
    for (int i = 0; i < 4; ++i) ra[i] = *(const u16x8*)(pa + i * 8);
#pragma unroll
    for (int i = 0; i < 2; ++i) rb[i] = *(const u16x8*)(pb + i * 8);

    for (int k0 = 0; k0 < D_DIM; k0 += 64) {
        __syncthreads();
#pragma unroll
        for (int i = 0; i < 4; ++i) *(u16x8*)&Al[ar][ah * 32 + i * 8] = ra[i];
#pragma unroll
        for (int i = 0; i < 2; ++i) *(u16x8*)&Bl[br][bs * 16 + i * 8] = rb[i];
        __syncthreads();
        if (k0 + 64 < D_DIM) {
#pragma unroll
            for (int i = 0; i < 4; ++i) ra[i] = *(const u16x8*)(pa + k0 + 64 + i * 8);
#pragma unroll
            for (int i = 0; i < 2; ++i) rb[i] = *(const u16x8*)(pb + k0 + 64 + i * 8);
        }
#pragma unroll
        for (int kh = 0; kh < 2; ++kh) {
            bf16x8 af[4];
#pragma unroll
            for (int mt = 0; mt < 4; ++mt)
                af[mt] = *(const bf16x8*)&Al[wm * 64 + mt * 16 + col16][kh * 32 + quad * 8];
#pragma unroll
            for (int nt = 0; nt < 2; ++nt) {
                bf16x8 bfr = *(const bf16x8*)&Bl[wn * 32 + nt * 16 + col16][kh * 32 + quad * 8];
#pragma unroll
                for (int mt = 0; mt < 4; ++mt)
                    acc[mt][nt] = MFMA16(af[mt], bfr, acc[mt][nt]);
            }
        }
    }
#pragma unroll
    for (int nt = 0; nt < 2; ++nt) {
        int col = bn * 64 + wn * 32 + nt * 16 + col16;
        float bv = bout[col];
#pragma unroll
        for (int mt = 0; mt < 4; ++mt) {
            int row0 = bm * 128 + wm * 64 + mt * 16 + quad * 4;
#pragma unroll
            for (int rr = 0; rr < 4; ++rr) {
                size_t idx = (size_t)(row0 + rr) * D_DIM + col;
                out[idx] = acc[mt][nt][rr] + x[idx] + bv;
            }
        }
    }
}

// ---------------------------------------------------------------------------
extern "C" void kernel_launch(void* const* d_in, const int* in_sizes, int n_in,
                              void* d_out, int out_size, void* d_ws, size_t ws_size,
                              hipStream_t stream) {
    const float* x    = (const float*)d_in[0];
    const float* Wq   = (const float*)d_in[1];
    const float* bq   = (const float*)d_in[2];
    const float* Wv   = (const float*)d_in[3];
    const float* Wout = (const float*)d_in[4];
    const float* bout = (const float*)d_in[5];
    const int*   mask = (const int*)d_in[6];
    float* out = (float*)d_out;

    char* ws = (char*)d_ws;
    u16*   Qbf   = (u16*)(ws);                         // 8 MB
    u16*   QT    = (u16*)(ws + (8u << 20));            // 8 MB
    u16*   xb    = (u16*)(ws + (16u << 20));           // 8 MB (reused as attnO)
    u16*   wqb   = (u16*)(ws + (24u << 20));           // 2 MB
    u16*   W2    = (u16*)(ws + (26u << 20));           // 2 MB
    float* Mpart = (float*)(ws + (28u << 20));         // 1 MB (4 partials)
    float* sq05  = (float*)(ws + (29u << 20));         // 256 KB
    u16*   attnO = xb;   // xb dead after k_qproj

    k_cvt<<<dim3(2560), dim3(256), 0, stream>>>(x, Wq, xb, wqb);
    k_precomp_M<<<dim3(8, 16, 4), dim3(256), 0, stream>>>(Wq, Wv, Mpart);
    k_precomp_W2<<<dim3(16, 16), dim3(256), 0, stream>>>(Mpart, Wout, W2);
    k_qproj<<<dim3(32, 16), dim3(256), 0, stream>>>(xb, wqb, bq, mask, Qbf, QT, sq05);
    k_flash<<<dim3(1024), dim3(256), 0, stream>>>(Qbf, QT, sq05, attnO);
    k_oproj<<<dim3(32, 16), dim3(256), 0, stream>>>(attnO, W2, x, bout, out);
}

// Round 7
// 211.691 us; speedup vs baseline: 1.2743x; 1.0662x over previous
//
#include <hip/hip_runtime.h>

#define S_LEN 2048
#define D_DIM 1024
#define NH    16
#define DHEAD 64

typedef float f32x4 __attribute__((ext_vector_type(4)));
typedef __bf16 bf16x8 __attribute__((ext_vector_type(8)));
typedef unsigned short u16;
typedef unsigned int u32;
typedef unsigned short u16x8 __attribute__((ext_vector_type(8)));
typedef unsigned short u16x4 __attribute__((ext_vector_type(4)));

__device__ __forceinline__ u16 f2bf(float f) {
    union { float f; unsigned u; } c; c.f = f;
    unsigned u = c.u + 0x7fffu + ((c.u >> 16) & 1u);
    return (u16)(u >> 16);
}

#if __has_builtin(__builtin_amdgcn_exp2f)
#define EXP2(x) __builtin_amdgcn_exp2f(x)
#else
#define EXP2(x) exp2f(x)
#endif

// 0.25*log2(e), 0.125*log2(e)
#define C_QK  0.36067376022224085f
#define C_SQ  0.18033688011112043f

#define MFMA16(a, b, c) __builtin_amdgcn_mfma_f32_16x16x32_bf16((a), (b), (c), 0, 0, 0)

// pack two f32 into bf16 pair (truncation; bias cancels in softmax normalize)
__device__ __forceinline__ u32 pack_bf(float lo, float hi) {
    union { float f; u32 u; } a, b; a.f = lo; b.f = hi;
    return (b.u & 0xFFFF0000u) | (a.u >> 16);
}

// ---------------------------------------------------------------------------
// Convert x (4.19M) and Wq (1.05M) fp32 -> bf16 once. 8 elems/thread.
__global__ __launch_bounds__(256) void k_cvt(
    const float* __restrict__ x, const float* __restrict__ wq,
    u16* __restrict__ xb, u16* __restrict__ wqb) {
    const int bid = blockIdx.x;
    const float* s; u16* d; size_t base;
    if (bid < 2048) { s = x;  d = xb;  base = (size_t)bid * 2048 + threadIdx.x * 8; }
    else           { s = wq; d = wqb; base = (size_t)(bid - 2048) * 2048 + threadIdx.x * 8; }
    f32x4 a = *(const f32x4*)(s + base);
    f32x4 b = *(const f32x4*)(s + base + 4);
    u16x8 o;
#pragma unroll
    for (int e = 0; e < 4; ++e) { o[e] = f2bf(a[e]); o[e + 4] = f2bf(b[e]); }
    *(u16x8*)(d + base) = o;
}

// ---------------------------------------------------------------------------
// Mpart[z][h*64+j][f] = partial_z sum_e Wq[e, h*64+j] * Wv[e, h*64+f]
__global__ __launch_bounds__(256) void k_precomp_M(
    const float* __restrict__ Wq, const float* __restrict__ Wv, float* __restrict__ Mpart) {
    __shared__ float red[4][8][64];
    const int tid = threadIdx.x;
    const int f = tid & 63, ks = tid >> 6;
    const int jg = blockIdx.x, h = blockIdx.y, z = blockIdx.z;
    const float* vcol = Wv + h * DHEAD + f;
    const float* qcol = Wq + h * DHEAD + jg * 8;
    float acc[8];
#pragma unroll
    for (int jj = 0; jj < 8; ++jj) acc[jj] = 0.f;
    const int e0 = z * 256 + ks * 64;
    for (int e = e0; e < e0 + 64; ++e) {
        float v = vcol[(size_t)e * D_DIM];
        const float* qr = qcol + (size_t)e * D_DIM;
#pragma unroll
        for (int jj = 0; jj < 8; ++jj) acc[jj] += qr[jj] * v;
    }
#pragma unroll
    for (int jj = 0; jj < 8; ++jj) red[ks][jj][f] = acc[jj];
    __syncthreads();
    for (int t = tid; t < 512; t += 256) {
        int jj = t >> 6, ff = t & 63;
        float s = red[0][jj][ff] + red[1][jj][ff] + red[2][jj][ff] + red[3][jj][ff];
        Mpart[(size_t)z * (NH * 64 * 64) + ((size_t)(h * 64 + jg * 8 + jj)) * 64 + ff] = s * 0.125f;
    }
}

// ---------------------------------------------------------------------------
// W2[o, h*64+j] = sum_f (sum_z Mpart[z,h,j,f]) * Wout[o, h*64+f]   (bf16 out)
__global__ __launch_bounds__(256) void k_precomp_W2(
    const float* __restrict__ Mpart, const float* __restrict__ Wout, u16* __restrict__ W2) {
    __shared__ float Ms[64][65];
    __shared__ float Ws[64][65];
    const int tid = threadIdx.x;
    const int ob = blockIdx.x, h = blockIdx.y;
    {
        int rr = tid >> 2, seg = tid & 3;
        const size_t mo = ((size_t)(h * 64 + rr)) * 64 + seg * 16;
        const float* ws = Wout + (size_t)(ob * 64 + rr) * D_DIM + h * DHEAD + seg * 16;
#pragma unroll
        for (int e = 0; e < 16; ++e) {
            Ms[rr][seg * 16 + e] = Mpart[mo + e] + Mpart[mo + e + 65536]
                                 + Mpart[mo + e + 131072] + Mpart[mo + e + 196608];
            Ws[rr][seg * 16 + e] = ws[e];
        }
    }
    __syncthreads();
    int j = tid & 63, o0 = (tid >> 6) * 16;
    for (int oo = o0; oo < o0 + 16; ++oo) {
        float acc = 0.f;
#pragma unroll
        for (int f = 0; f < 64; ++f) acc += Ms[j][f] * Ws[oo][f];
        W2[(size_t)(ob * 64 + oo) * D_DIM + h * DHEAD + j] = f2bf(acc);
    }
}

// ---------------------------------------------------------------------------
// Q projection, bf16, 64x64 tile (bn = head), grid (64,16) = 1024 blocks.
// Epilogue: Qbf + in-LDS transpose -> coalesced QT + sq05.
__global__ __launch_bounds__(256) void k_qproj(
    const u16* __restrict__ xb, const u16* __restrict__ wqb,
    const float* __restrict__ bq, const int* __restrict__ mask,
    u16* __restrict__ Qbf, u16* __restrict__ QT, float* __restrict__ sq05) {
    __shared__ u16 Al[64][72];
    __shared__ u16 Bl[64][72];
    __shared__ float sqred[64];
    const int tid = threadIdx.x, lane = tid & 63, w = tid >> 6;
    const int wm = w & 1, wn = w >> 1;
    const int col16 = lane & 15, quad = lane >> 4;
    const int bm = blockIdx.x, bn = blockIdx.y;   // bn = head

    f32x4 acc[2][2];
    const f32x4 z4 = {0.f, 0.f, 0.f, 0.f};
#pragma unroll
    for (int i = 0; i < 2; ++i)
#pragma unroll
        for (int j = 0; j < 2; ++j) acc[i][j] = z4;

    const int ar = tid >> 2, as = tid & 3;
    const u16* pa = xb + (size_t)(bm * 64 + ar) * D_DIM + as * 16;
    const u16* pb = wqb + (size_t)(bn * 64 + ar) * D_DIM + as * 16;

    u16x8 ra[2], rb[2];
#pragma unroll
    for (int i = 0; i < 2; ++i) ra[i] = *(const u16x8*)(pa + i * 8);
#pragma unroll
    for (int i = 0; i < 2; ++i) rb[i] = *(const u16x8*)(pb + i * 8);

    for (int k0 = 0; k0 < D_DIM; k0 += 64) {
        __syncthreads();
#pragma unroll
        for (int i = 0; i < 2; ++i) *(u16x8*)&Al[ar][as * 16 + i * 8] = ra[i];
#pragma unroll
        for (int i = 0; i < 2; ++i) *(u16x8*)&Bl[ar][as * 16 + i * 8] = rb[i];
        __syncthreads();
        if (k0 + 64 < D_DIM) {
#pragma unroll
            for (int i = 0; i < 2; ++i) ra[i] = *(const u16x8*)(pa + k0 + 64 + i * 8);
#pragma unroll
            for (int i = 0; i < 2; ++i) rb[i] = *(const u16x8*)(pb + k0 + 64 + i * 8);
        }
#pragma unroll
        for (int kh = 0; kh < 2; ++kh) {
            bf16x8 af[2];
#pragma unroll
            for (int mt = 0; mt < 2; ++mt)
                af[mt] = *(const bf16x8*)&Al[wm * 32 + mt * 16 + col16][kh * 32 + quad * 8];
#pragma unroll
            for (int nt = 0; nt < 2; ++nt) {
                bf16x8 bfr = *(const bf16x8*)&Bl[wn * 32 + nt * 16 + col16][kh * 32 + quad * 8];
#pragma unroll
                for (int mt = 0; mt < 2; ++mt)
                    acc[mt][nt] = MFMA16(af[mt], bfr, acc[mt][nt]);
            }
        }
    }

    const int h = bn;
    const int bb = (bm * 64) >> 11, s0 = (bm * 64) & 2047;
    f32x4 ssum[2];
#pragma unroll
    for (int mt = 0; mt < 2; ++mt) ssum[mt] = z4;

    u16 qv16[2][2][4];
#pragma unroll
    for (int nt = 0; nt < 2; ++nt) {
        int dloc = wn * 32 + nt * 16 + col16;
        int col = bn * 64 + dloc;
        float bqv = bq[col];
#pragma unroll
        for (int mt = 0; mt < 2; ++mt) {
            int row0 = bm * 64 + wm * 32 + mt * 16 + quad * 4;
#pragma unroll
            for (int rr = 0; rr < 4; ++rr) {
                float qv = acc[mt][nt][rr] + bqv;
                ssum[mt][rr] += qv * qv;
                u16 bv = f2bf(qv);
                qv16[nt][mt][rr] = bv;
                Qbf[(size_t)(row0 + rr) * D_DIM + col] = bv;
            }
        }
    }
    // ||q||^2: 16-lane reduce (this wave's 32 d), then cross-wn combine
    float vred[2][4];
#pragma unroll
    for (int mt = 0; mt < 2; ++mt)
#pragma unroll
        for (int rr = 0; rr < 4; ++rr) {
            float v = ssum[mt][rr];
            v += __shfl_xor(v, 1); v += __shfl_xor(v, 2);
            v += __shfl_xor(v, 4); v += __shfl_xor(v, 8);
            vred[mt][rr] = v;
        }
    __syncthreads();   // MFMA-loop LDS reads done; Al reusable
    // transpose tile: Al[d][s_local]
#pragma unroll
    for (int nt = 0; nt < 2; ++nt) {
        int dloc = wn * 32 + nt * 16 + col16;
#pragma unroll
        for (int mt = 0; mt < 2; ++mt) {
            int sl = wm * 32 + mt * 16 + quad * 4;
#pragma unroll
            for (int rr = 0; rr < 4; ++rr)
                Al[dloc][sl + rr] = qv16[nt][mt][rr];
        }
    }
    if (wn == 1 && col16 == 0) {
#pragma unroll
        for (int mt = 0; mt < 2; ++mt)
#pragma unroll
            for (int rr = 0; rr < 4; ++rr)
                sqred[wm * 32 + mt * 16 + quad * 4 + rr] = vred[mt][rr];
    }
    __syncthreads();
    if (wn == 0 && col16 == 0) {
#pragma unroll
        for (int mt = 0; mt < 2; ++mt)
#pragma unroll
            for (int rr = 0; rr < 4; ++rr) {
                int rloc = wm * 32 + mt * 16 + quad * 4 + rr;
                int sidx = s0 + rloc;
                float v = vred[mt][rr] + sqred[rloc];
                float o = mask[bb * S_LEN + sidx] ? v * C_SQ : 1e30f;
                sq05[((size_t)(bb * NH + h)) * S_LEN + sidx] = o;
            }
    }
    // QT write, fully coalesced: 4 threads per d-row, 32B each
    {
        int d = tid >> 2, ch = tid & 3;
        u16* dst = QT + ((size_t)(bb * NH + h) * DHEAD + d) * S_LEN + s0 + ch * 16;
        *(u16x8*)dst = *(const u16x8*)&Al[d][ch * 16];
        *(u16x8*)(dst + 8) = *(const u16x8*)&Al[d][ch * 16 + 8];
    }
}

// ---------------------------------------------------------------------------
// Fused L2 attention, transpose-free, kt-split (R5 structure, 128q tile).
// Edits vs R5: va loads hoisted above exp; lsum via ones-A MFMA.
__global__ __launch_bounds__(256, 2) void k_flash(
    const u16* __restrict__ Qbf, const u16* __restrict__ QT,
    const float* __restrict__ sq05, u16* __restrict__ attnO) {
    __shared__ __align__(16) char smem[34816];
    u16* Kt  = (u16*)smem;              // [128][64] u16, xor-swizzled cols
    u16* KtT = (u16*)(smem + 16384);    // [64][128] u16, xor-swizzled cols
    float* sql = (float*)(smem + 32768);// [128]

    const int tid = threadIdx.x, lane = tid & 63, w = tid >> 6;
    const int col16 = lane & 15, quad = lane >> 4;
    const int wq = w & 1, wk = w >> 1;
    const int qt = blockIdx.x & 15;
    const int h = (blockIdx.x >> 4) & 15;
    const int b = blockIdx.x >> 8;
    const u16* qbase = Qbf + (size_t)b * S_LEN * D_DIM + h * DHEAD;
    const u16* qtbase = QT + ((size_t)(b * NH + h)) * DHEAD * S_LEN;
    const float* sqb = sq05 + ((size_t)(b * NH + h)) * S_LEN;

    // loop-invariant Q^T B-fragments (global, once)
    bf16x8 qb[4][2];
#pragma unroll
    for (int nq = 0; nq < 4; ++nq)
#pragma unroll
        for (int k0 = 0; k0 < 2; ++k0)
            qb[nq][k0] = *(const bf16x8*)(qbase +
                (size_t)(qt * 128 + wq * 64 + nq * 16 + col16) * D_DIM + k0 * 32 + quad * 8);

    // Kt read offset closed form: krow(kt,kbh) = krow00 + kt*2048 + kbh*256
    const int r00 = wk * 64 + (col16 >> 2) * 8 + (col16 & 3);
    const int swzA = (col16 & 3) | (((col16 >> 2) & 1) << 2);
    const int krow00 = r00 * 64 + (quad ^ swzA) * 8;
    const int sq00 = wk * 64 + quad * 8;
    // KtT read offsets per dblk (kt handled by ^32)
    int vrow[4];
#pragma unroll
    for (int dblk = 0; dblk < 4; ++dblk) {
        int rT = dblk * 16 + col16;
        vrow[dblk] = rT * 128 + ((wk * 8 + quad) ^ (rT & 7)) * 8;
    }

    // staging assignments
    const int kr = tid >> 1, ks = tid & 1;
    const int td = tid >> 2, ts = tid & 3;
    const int kswz = (kr & 3) | (((kr >> 3) & 1) << 2);
    const int tswz = td & 7;
    const u16* ksrc = qbase + (size_t)kr * D_DIM + ks * 32;
    const u16* tsrc = qtbase + (size_t)td * S_LEN + ts * 32;

    u16x8 pk[4], pt[4];
    float sv = 0.f;
#pragma unroll
    for (int i = 0; i < 4; ++i) pk[i] = *(const u16x8*)(ksrc + i * 8);
#pragma unroll
    for (int i = 0; i < 4; ++i) pt[i] = *(const u16x8*)(tsrc + i * 8);
    if (tid < 128) sv = sqb[tid];

    f32x4 Oacc[4][4], lacc[4];
    const f32x4 z4 = {0.f, 0.f, 0.f, 0.f};
#pragma unroll
    for (int n = 0; n < 4; ++n) {
        lacc[n] = z4;
#pragma unroll
        for (int d = 0; d < 4; ++d) Oacc[d][n] = z4;
    }
    bf16x8 ones;
    {
        union { u16x8 u; bf16x8 b; } cv;
#pragma unroll
        for (int e = 0; e < 8; ++e) cv.u[e] = 0x3F80;
        ones = cv.b;
    }

    for (int j = 0; j < S_LEN / 128; ++j) {
        __syncthreads();
#pragma unroll
        for (int i = 0; i < 4; ++i)
            *(u16x8*)(Kt + kr * 64 + ((ks * 4 + i) ^ kswz) * 8) = pk[i];
#pragma unroll
        for (int i = 0; i < 4; ++i)
            *(u16x8*)(KtT + td * 128 + ((ts * 4 + i) ^ tswz) * 8) = pt[i];
        if (tid < 128) sql[tid] = sv;
        __syncthreads();

        int jn = (j + 1) & 15;
        {
            const u16* kn = ksrc + (size_t)jn * 128 * D_DIM;
            const u16* tn = tsrc + (size_t)jn * 128;
#pragma unroll
            for (int i = 0; i < 4; ++i) pk[i] = *(const u16x8*)(kn + i * 8);
#pragma unroll
            for (int i = 0; i < 4; ++i) pt[i] = *(const u16x8*)(tn + i * 8);
            if (tid < 128) sv = sqb[jn * 128 + tid];
        }

        // two key-half rounds: S^T (32 keys x 64 q) -> exp/pack -> PV
        for (int kt = 0; kt < 2; ++kt) {
            f32x4 sacc[2][4];
#pragma unroll
            for (int kbh = 0; kbh < 2; ++kbh)
#pragma unroll
                for (int nq = 0; nq < 4; ++nq) sacc[kbh][nq] = z4;
#pragma unroll
            for (int kbh = 0; kbh < 2; ++kbh) {
                int kro = krow00 + kt * 2048 + kbh * 256;
                bf16x8 a0 = *(const bf16x8*)(Kt + kro);
                bf16x8 a1 = *(const bf16x8*)(Kt + (kro ^ 32));
#pragma unroll
                for (int nq = 0; nq < 4; ++nq) {
                    sacc[kbh][nq] = MFMA16(a0, qb[nq][0], sacc[kbh][nq]);
                    sacc[kbh][nq] = MFMA16(a1, qb[nq][1], sacc[kbh][nq]);
                }
            }

            // hoist V-fragment LDS reads: latency hides under the exp chain
            bf16x8 va[4];
#pragma unroll
            for (int dblk = 0; dblk < 4; ++dblk)
                va[dblk] = *(const bf16x8*)(KtT + (vrow[dblk] ^ (kt * 32)));

            u32 pf[4][4];
#pragma unroll
            for (int kbh = 0; kbh < 2; ++kbh) {
                f32x4 sqv = *(const f32x4*)(sql + sq00 + kt * 32 + kbh * 4);
#pragma unroll
                for (int nq = 0; nq < 4; ++nq) {
                    float p0 = EXP2(fmaf(sacc[kbh][nq][0], C_QK, -sqv[0]));
                    float p1 = EXP2(fmaf(sacc[kbh][nq][1], C_QK, -sqv[1]));
                    float p2 = EXP2(fmaf(sacc[kbh][nq][2], C_QK, -sqv[2]));
                    float p3 = EXP2(fmaf(sacc[kbh][nq][3], C_QK, -sqv[3]));
                    pf[nq][kbh * 2]     = pack_bf(p0, p1);
                    pf[nq][kbh * 2 + 1] = pack_bf(p2, p3);
                }
            }

#pragma unroll
            for (int nq = 0; nq < 4; ++nq) {
                union { u32 u[4]; bf16x8 b; } pb;
#pragma unroll
                for (int i = 0; i < 4; ++i) pb.u[i] = pf[nq][i];
                lacc[nq] = MFMA16(ones, pb.b, lacc[nq]);   // key-sums, rows replicated
#pragma unroll
                for (int dblk = 0; dblk < 4; ++dblk)
                    Oacc[dblk][nq] = MFMA16(va[dblk], pb.b, Oacc[dblk][nq]);
            }
        }
    }

    // cross-wave (key-half) combine + epilogue
    __syncthreads();
    float* Obuf = (float*)smem;                 // [2][16][64] f32x4 = 32 KB
    float* lred = (float*)(smem + 32768);       // [2][4][64]
    if (wk == 1) {
#pragma unroll
        for (int dblk = 0; dblk < 4; ++dblk)
#pragma unroll
            for (int nq = 0; nq < 4; ++nq)
                *(f32x4*)(Obuf + ((wq * 16 + dblk * 4 + nq) * 64 + lane) * 4) = Oacc[dblk][nq];
#pragma unroll
        for (int nq = 0; nq < 4; ++nq)
            lred[(wq * 4 + nq) * 64 + lane] = lacc[nq][0];
    }
    __syncthreads();
    if (wk == 0) {
        float rinv[4];
#pragma unroll
        for (int nq = 0; nq < 4; ++nq)
            rinv[nq] = 1.f / (lacc[nq][0] + lred[(wq * 4 + nq) * 64 + lane]);
        u16* obase = attnO + (size_t)b * S_LEN * D_DIM + h * DHEAD;
#pragma unroll
        for (int dblk = 0; dblk < 4; ++dblk)
#pragma unroll
            for (int nq = 0; nq < 4; ++nq) {
                f32x4 o = Oacc[dblk][nq] + *(const f32x4*)(Obuf + ((wq * 16 + dblk * 4 + nq) * 64 + lane) * 4);
                int q = qt * 128 + wq * 64 + nq * 16 + col16;
                u16x4 pkk;
#pragma unroll
                for (int rr = 0; rr < 4; ++rr) pkk[rr] = f2bf(o[rr] * rinv[nq]);
                *(u16x4*)(obase + (size_t)q * D_DIM + dblk * 16 + quad * 4) = pkk;
            }
    }
}

// ---------------------------------------------------------------------------
// Output GEMM, 64x64 tile, grid (64,16): out[s,o] = x[s,o]+bout[o]+attnO·W2^T
__global__ __launch_bounds__(256) void k_oproj(
    const u16* __restrict__ attnO, const u16* __restrict__ W2,
    const float* __restrict__ x, const float* __restrict__ bout, float* __restrict__ out) {
    __shared__ u16 Al[64][72];
    __shared__ u16 Bl[64][72];
    const int tid = threadIdx.x, lane = tid & 63, w = tid >> 6;
    const int wm = w & 1, wn = w >> 1;
    const int col16 = lane & 15, quad = lane >> 4;
    const int bm = blockIdx.x, bn = blockIdx.y;

    f32x4 acc[2][2];
    const f32x4 z4 = {0.f, 0.f, 0.f, 0.f};
#pragma unroll
    for (int i = 0; i < 2; ++i)
#pragma unroll
        for (int j = 0; j < 2; ++j) acc[i][j] = z4;

    const int ar = tid >> 2, as = tid & 3;
    const u16* pa = attnO + (size_t)(bm * 64 + ar) * D_DIM + as * 16;
    const u16* pb = W2 + (size_t)(bn * 64 + ar) * D_DIM + as * 16;

    u16x8 ra[2], rb[2];
#pragma unroll
    for (int i = 0; i < 2; ++i) ra[i] = *(const u16x8*)(pa + i * 8);
#pragma unroll
    for (int i = 0; i < 2; ++i) rb[i] = *(const u16x8*)(pb + i * 8);

    for (int k0 = 0; k0 < D_DIM; k0 += 64) {
        __syncthreads();
#pragma unroll
        for (int i = 0; i < 2; ++i) *(u16x8*)&Al[ar][as * 16 + i * 8] = ra[i];
#pragma unroll
        for (int i = 0; i < 2; ++i) *(u16x8*)&Bl[ar][as * 16 + i * 8] = rb[i];
        __syncthreads();
        if (k0 + 64 < D_DIM) {
#pragma unroll
            for (int i = 0; i < 2; ++i) ra[i] = *(const u16x8*)(pa + k0 + 64 + i * 8);
#pragma unroll
            for (int i = 0; i < 2; ++i) rb[i] = *(const u16x8*)(pb + k0 + 64 + i * 8);
        }
#pragma unroll
        for (int kh = 0; kh < 2; ++kh) {
            bf16x8 af[2];
#pragma unroll
            for (int mt = 0; mt < 2; ++mt)
                af[mt] = *(const bf16x8*)&Al[wm * 32 + mt * 16 + col16][kh * 32 + quad * 8];
#pragma unroll
            for (int nt = 0; nt < 2; ++nt) {
                bf16x8 bfr = *(const bf16x8*)&Bl[wn * 32 + nt * 16 + col16][kh * 32 + quad * 8];
#pragma unroll
                for (int mt = 0; mt < 2; ++mt)
                    acc[mt][nt] = MFMA16(af[mt], bfr, acc[mt][nt]);
            }
        }
    }
#pragma unroll
    for (int nt = 0; nt < 2; ++nt) {
        int col = bn * 64 + wn * 32 + nt * 16 + col16;
        float bv = bout[col];
#pragma unroll
        for (int mt = 0; mt < 2; ++mt) {
            int row0 = bm * 64 + wm * 32 + mt * 16 + quad * 4;
#pragma unroll
            for (int rr = 0; rr < 4; ++rr) {
                size_t idx = (size_t)(row0 + rr) * D_DIM + col;
                out[idx] = acc[mt][nt][rr] + x[idx] + bv;
            }
        }
    }
}

// ---------------------------------------------------------------------------
extern "C" void kernel_launch(void* const* d_in, const int* in_sizes, int n_in,
                              void* d_out, int out_size, void* d_ws, size_t ws_size,
                              hipStream_t stream) {
    const float* x    = (const float*)d_in[0];
    const float* Wq   = (const float*)d_in[1];
    const float* bq   = (const float*)d_in[2];
    const float* Wv   = (const float*)d_in[3];
    const float* Wout = (const float*)d_in[4];
    const float* bout = (const float*)d_in[5];
    const int*   mask = (const int*)d_in[6];
    float* out = (float*)d_out;

    char* ws = (char*)d_ws;
    u16*   Qbf   = (u16*)(ws);                         // 8 MB
    u16*   QT    = (u16*)(ws + (8u << 20));            // 8 MB
    u16*   xb    = (u16*)(ws + (16u << 20));           // 8 MB (reused as attnO)
    u16*   wqb   = (u16*)(ws + (24u << 20));           // 2 MB
    u16*   W2    = (u16*)(ws + (26u << 20));           // 2 MB
    float* Mpart = (float*)(ws + (28u << 20));         // 1 MB (4 partials)
    float* sq05  = (float*)(ws + (29u << 20));         // 256 KB
    u16*   attnO = xb;   // xb dead after k_qproj

    k_cvt<<<dim3(2560), dim3(256), 0, stream>>>(x, Wq, xb, wqb);
    k_precomp_M<<<dim3(8, 16, 4), dim3(256), 0, stream>>>(Wq, Wv, Mpart);
    k_precomp_W2<<<dim3(16, 16), dim3(256), 0, stream>>>(Mpart, Wout, W2);
    k_qproj<<<dim3(64, 16), dim3(256), 0, stream>>>(xb, wqb, bq, mask, Qbf, QT, sq05);
    k_flash<<<dim3(512), dim3(256), 0, stream>>>(Qbf, QT, sq05, attnO);
    k_oproj<<<dim3(64, 16), dim3(256), 0, stream>>>(attnO, W2, x, bout, out);
}

// Round 8
// 202.987 us; speedup vs baseline: 1.3289x; 1.0429x over previous
//
#include <hip/hip_runtime.h>

#define S_LEN 2048
#define D_DIM 1024
#define NH    16
#define DHEAD 64

typedef float f32x4 __attribute__((ext_vector_type(4)));
typedef __bf16 bf16x8 __attribute__((ext_vector_type(8)));
typedef unsigned short u16;
typedef unsigned int u32;
typedef unsigned short u16x8 __attribute__((ext_vector_type(8)));
typedef unsigned short u16x4 __attribute__((ext_vector_type(4)));

__device__ __forceinline__ u16 f2bf(float f) {
    union { float f; unsigned u; } c; c.f = f;
    unsigned u = c.u + 0x7fffu + ((c.u >> 16) & 1u);
    return (u16)(u >> 16);
}

#if __has_builtin(__builtin_amdgcn_exp2f)
#define EXP2(x) __builtin_amdgcn_exp2f(x)
#else
#define EXP2(x) exp2f(x)
#endif

// 0.25*log2(e), 0.125*log2(e)
#define C_QK  0.36067376022224085f
#define C_SQ  0.18033688011112043f

#define MFMA16(a, b, c) __builtin_amdgcn_mfma_f32_16x16x32_bf16((a), (b), (c), 0, 0, 0)

// pack two f32 into bf16 pair (truncation; bias cancels in softmax normalize)
__device__ __forceinline__ u32 pack_bf(float lo, float hi) {
    union { float f; u32 u; } a, b; a.f = lo; b.f = hi;
    return (b.u & 0xFFFF0000u) | (a.u >> 16);
}

// ---------------------------------------------------------------------------
// Convert x (4.19M) and Wq (1.05M) fp32 -> bf16 once. 8 elems/thread.
__global__ __launch_bounds__(256) void k_cvt(
    const float* __restrict__ x, const float* __restrict__ wq,
    u16* __restrict__ xb, u16* __restrict__ wqb) {
    const int bid = blockIdx.x;
    const float* s; u16* d; size_t base;
    if (bid < 2048) { s = x;  d = xb;  base = (size_t)bid * 2048 + threadIdx.x * 8; }
    else           { s = wq; d = wqb; base = (size_t)(bid - 2048) * 2048 + threadIdx.x * 8; }
    f32x4 a = *(const f32x4*)(s + base);
    f32x4 b = *(const f32x4*)(s + base + 4);
    u16x8 o;
#pragma unroll
    for (int e = 0; e < 4; ++e) { o[e] = f2bf(a[e]); o[e + 4] = f2bf(b[e]); }
    *(u16x8*)(d + base) = o;
}

// ---------------------------------------------------------------------------
// Mpart[z][h*64+j][f] = partial_z sum_e Wq[e, h*64+j] * Wv[e, h*64+f]
__global__ __launch_bounds__(256) void k_precomp_M(
    const float* __restrict__ Wq, const float* __restrict__ Wv, float* __restrict__ Mpart) {
    __shared__ float red[4][8][64];
    const int tid = threadIdx.x;
    const int f = tid & 63, ks = tid >> 6;
    const int jg = blockIdx.x, h = blockIdx.y, z = blockIdx.z;
    const float* vcol = Wv + h * DHEAD + f;
    const float* qcol = Wq + h * DHEAD + jg * 8;
    float acc[8];
#pragma unroll
    for (int jj = 0; jj < 8; ++jj) acc[jj] = 0.f;
    const int e0 = z * 256 + ks * 64;
    for (int e = e0; e < e0 + 64; ++e) {
        float v = vcol[(size_t)e * D_DIM];
        const float* qr = qcol + (size_t)e * D_DIM;
#pragma unroll
        for (int jj = 0; jj < 8; ++jj) acc[jj] += qr[jj] * v;
    }
#pragma unroll
    for (int jj = 0; jj < 8; ++jj) red[ks][jj][f] = acc[jj];
    __syncthreads();
    for (int t = tid; t < 512; t += 256) {
        int jj = t >> 6, ff = t & 63;
        float s = red[0][jj][ff] + red[1][jj][ff] + red[2][jj][ff] + red[3][jj][ff];
        Mpart[(size_t)z * (NH * 64 * 64) + ((size_t)(h * 64 + jg * 8 + jj)) * 64 + ff] = s * 0.125f;
    }
}

// ---------------------------------------------------------------------------
// W2[o, h*64+j] = sum_f (sum_z Mpart[z,h,j,f]) * Wout[o, h*64+f]   (bf16 out)
__global__ __launch_bounds__(256) void k_precomp_W2(
    const float* __restrict__ Mpart, const float* __restrict__ Wout, u16* __restrict__ W2) {
    __shared__ float Ms[64][65];
    __shared__ float Ws[64][65];
    const int tid = threadIdx.x;
    const int ob = blockIdx.x, h = blockIdx.y;
    {
        int rr = tid >> 2, seg = tid & 3;
        const size_t mo = ((size_t)(h * 64 + rr)) * 64 + seg * 16;
        const float* ws = Wout + (size_t)(ob * 64 + rr) * D_DIM + h * DHEAD + seg * 16;
#pragma unroll
        for (int e = 0; e < 16; ++e) {
            Ms[rr][seg * 16 + e] = Mpart[mo + e] + Mpart[mo + e + 65536]
                                 + Mpart[mo + e + 131072] + Mpart[mo + e + 196608];
            Ws[rr][seg * 16 + e] = ws[e];
        }
    }
    __syncthreads();
    int j = tid & 63, o0 = (tid >> 6) * 16;
    for (int oo = o0; oo < o0 + 16; ++oo) {
        float acc = 0.f;
#pragma unroll
        for (int f = 0; f < 64; ++f) acc += Ms[j][f] * Ws[oo][f];
        W2[(size_t)(ob * 64 + oo) * D_DIM + h * DHEAD + j] = f2bf(acc);
    }
}

// ---------------------------------------------------------------------------
// Q projection, bf16, 128x128 tile, 512 threads (8 waves, 2x4), grid (32,8).
// Epilogue: Qbf + in-LDS transpose -> coalesced QT + sq05 (2 heads per tile).
__global__ __launch_bounds__(512, 4) void k_qproj(
    const u16* __restrict__ xb, const u16* __restrict__ wqb,
    const float* __restrict__ bq, const int* __restrict__ mask,
    u16* __restrict__ Qbf, u16* __restrict__ QT, float* __restrict__ sq05) {
    __shared__ __align__(16) char smem[38912];
    u16* Al = (u16*)smem;              // [128][72]
    u16* Bl = (u16*)(smem + 18432);    // [128][72]
    float* sqp = (float*)(smem + 36864); // [4][128]

    const int tid = threadIdx.x, lane = tid & 63, w = tid >> 6;
    const int wm = w & 1, wn = w >> 1;          // wn 0..3 (32-col quarters)
    const int col16 = lane & 15, quad = lane >> 4;
    const int bm = blockIdx.x, bn = blockIdx.y;

    f32x4 acc[4][2];
    const f32x4 z4 = {0.f, 0.f, 0.f, 0.f};
#pragma unroll
    for (int i = 0; i < 4; ++i)
#pragma unroll
        for (int j = 0; j < 2; ++j) acc[i][j] = z4;

    const int ar = tid >> 2, as = tid & 3;
    const u16* pa = xb + (size_t)(bm * 128 + ar) * D_DIM + as * 16;
    const u16* pb = wqb + (size_t)(bn * 128 + ar) * D_DIM + as * 16;

    u16x8 ra[2], rb[2];
#pragma unroll
    for (int i = 0; i < 2; ++i) ra[i] = *(const u16x8*)(pa + i * 8);
#pragma unroll
    for (int i = 0; i < 2; ++i) rb[i] = *(const u16x8*)(pb + i * 8);

    for (int k0 = 0; k0 < D_DIM; k0 += 64) {
        __syncthreads();
#pragma unroll
        for (int i = 0; i < 2; ++i) *(u16x8*)&Al[ar * 72 + as * 16 + i * 8] = ra[i];
#pragma unroll
        for (int i = 0; i < 2; ++i) *(u16x8*)&Bl[ar * 72 + as * 16 + i * 8] = rb[i];
        __syncthreads();
        if (k0 + 64 < D_DIM) {
#pragma unroll
            for (int i = 0; i < 2; ++i) ra[i] = *(const u16x8*)(pa + k0 + 64 + i * 8);
#pragma unroll
            for (int i = 0; i < 2; ++i) rb[i] = *(const u16x8*)(pb + k0 + 64 + i * 8);
        }
#pragma unroll
        for (int kh = 0; kh < 2; ++kh) {
            bf16x8 af[4];
#pragma unroll
            for (int mt = 0; mt < 4; ++mt)
                af[mt] = *(const bf16x8*)&Al[(wm * 64 + mt * 16 + col16) * 72 + kh * 32 + quad * 8];
#pragma unroll
            for (int nt = 0; nt < 2; ++nt) {
                bf16x8 bfr = *(const bf16x8*)&Bl[(wn * 32 + nt * 16 + col16) * 72 + kh * 32 + quad * 8];
#pragma unroll
                for (int mt = 0; mt < 4; ++mt)
                    acc[mt][nt] = MFMA16(af[mt], bfr, acc[mt][nt]);
            }
        }
    }

    // epilogue: bias, Qbf store, ||q||^2 partials, LDS transpose for QT
    const int hh = wn >> 1;                     // head half within tile
    f32x4 ssum[4];
#pragma unroll
    for (int mt = 0; mt < 4; ++mt) ssum[mt] = z4;

    u16 qv16[2][4][4];
#pragma unroll
    for (int nt = 0; nt < 2; ++nt) {
        int col = bn * 128 + wn * 32 + nt * 16 + col16;
        float bqv = bq[col];
#pragma unroll
        for (int mt = 0; mt < 4; ++mt) {
            int row0 = bm * 128 + wm * 64 + mt * 16 + quad * 4;
#pragma unroll
            for (int rr = 0; rr < 4; ++rr) {
                float qv = acc[mt][nt][rr] + bqv;
                ssum[mt][rr] += qv * qv;
                u16 bv = f2bf(qv);
                qv16[nt][mt][rr] = bv;
                Qbf[(size_t)(row0 + rr) * D_DIM + col] = bv;
            }
        }
    }
    // 16-lane reduce over this wave's 32 d
    float vred[4][4];
#pragma unroll
    for (int mt = 0; mt < 4; ++mt)
#pragma unroll
        for (int rr = 0; rr < 4; ++rr) {
            float v = ssum[mt][rr];
            v += __shfl_xor(v, 1); v += __shfl_xor(v, 2);
            v += __shfl_xor(v, 4); v += __shfl_xor(v, 8);
            vred[mt][rr] = v;
        }
    if (col16 == 0) {
#pragma unroll
        for (int mt = 0; mt < 4; ++mt)
#pragma unroll
            for (int rr = 0; rr < 4; ++rr)
                sqp[wn * 128 + wm * 64 + mt * 16 + quad * 4 + rr] = vred[mt][rr];
    }
    __syncthreads();   // MFMA frag reads done; Al/Bl reusable; sqp visible

    // transpose: Td[head][d][s_local], stride 130 u16
    u16* Td = (u16*)smem;
#pragma unroll
    for (int nt = 0; nt < 2; ++nt) {
        int dloc = (wn & 1) * 32 + nt * 16 + col16;
#pragma unroll
        for (int mt = 0; mt < 4; ++mt) {
            int sl = wm * 64 + mt * 16 + quad * 4;
#pragma unroll
            for (int rr = 0; rr < 4; ++rr)
                Td[(hh * 64 + dloc) * 130 + sl + rr] = qv16[nt][mt][rr];
        }
    }
    __syncthreads();

    const int bb = (bm * 128) >> 11, s0 = (bm * 128) & 2047;
    if (tid < 256) {
        int r = tid & 127, hh2 = tid >> 7;
        float v = sqp[(2 * hh2) * 128 + r] + sqp[(2 * hh2 + 1) * 128 + r];
        int sidx = s0 + r;
        float o = mask[bb * S_LEN + sidx] ? v * C_SQ : 1e30f;
        sq05[((size_t)(bb * NH + bn * 2 + hh2)) * S_LEN + sidx] = o;
    }
    {
        int dr = tid >> 2, ch = tid & 3;
        int hh3 = dr >> 6, d = dr & 63;
        u16* dst = QT + ((size_t)(bb * NH + bn * 2 + hh3) * DHEAD + d) * S_LEN + s0 + ch * 32;
        const u16* src = Td + (hh3 * 64 + d) * 130 + ch * 32;
#pragma unroll
        for (int i = 0; i < 4; ++i)
            *(u16x8*)(dst + i * 8) = *(const u16x8*)(src + i * 8);
    }
}

// ---------------------------------------------------------------------------
// Fused L2 attention, transpose-free, kt-split. XCD-swizzled: blocks of one
// (b,h) share blockIdx%8 -> same XCD L2 serves the K-stream re-reads.
__global__ __launch_bounds__(256, 2) void k_flash(
    const u16* __restrict__ Qbf, const u16* __restrict__ QT,
    const float* __restrict__ sq05, u16* __restrict__ attnO) {
    __shared__ __align__(16) char smem[34816];
    u16* Kt  = (u16*)smem;              // [128][64] u16, xor-swizzled cols
    u16* KtT = (u16*)(smem + 16384);    // [64][128] u16, xor-swizzled cols
    float* sql = (float*)(smem + 32768);// [128]

    const int tid = threadIdx.x, lane = tid & 63, w = tid >> 6;
    const int col16 = lane & 15, quad = lane >> 4;
    const int wq = w & 1, wk = w >> 1;
    const int bh = blockIdx.x & 31;      // (b,h) in low bits -> same XCD
    const int qt = blockIdx.x >> 5;
    const int h = bh & 15;
    const int b = bh >> 4;
    const u16* qbase = Qbf + (size_t)b * S_LEN * D_DIM + h * DHEAD;
    const u16* qtbase = QT + ((size_t)(b * NH + h)) * DHEAD * S_LEN;
    const float* sqb = sq05 + ((size_t)(b * NH + h)) * S_LEN;

    // loop-invariant Q^T B-fragments (global, once)
    bf16x8 qb[4][2];
#pragma unroll
    for (int nq = 0; nq < 4; ++nq)
#pragma unroll
        for (int k0 = 0; k0 < 2; ++k0)
            qb[nq][k0] = *(const bf16x8*)(qbase +
                (size_t)(qt * 128 + wq * 64 + nq * 16 + col16) * D_DIM + k0 * 32 + quad * 8);

    // Kt read offset closed form: krow(kt,kbh) = krow00 + kt*2048 + kbh*256
    const int r00 = wk * 64 + (col16 >> 2) * 8 + (col16 & 3);
    const int swzA = (col16 & 3) | (((col16 >> 2) & 1) << 2);
    const int krow00 = r00 * 64 + (quad ^ swzA) * 8;
    const int sq00 = wk * 64 + quad * 8;
    // KtT read offsets per dblk (kt handled by ^32)
    int vrow[4];
#pragma unroll
    for (int dblk = 0; dblk < 4; ++dblk) {
        int rT = dblk * 16 + col16;
        vrow[dblk] = rT * 128 + ((wk * 8 + quad) ^ (rT & 7)) * 8;
    }

    // staging assignments
    const int kr = tid >> 1, ks = tid & 1;
    const int td = tid >> 2, ts = tid & 3;
    const int kswz = (kr & 3) | (((kr >> 3) & 1) << 2);
    const int tswz = td & 7;
    const u16* ksrc = qbase + (size_t)kr * D_DIM + ks * 32;
    const u16* tsrc = qtbase + (size_t)td * S_LEN + ts * 32;

    u16x8 pk[4], pt[4];
    float sv = 0.f;
#pragma unroll
    for (int i = 0; i < 4; ++i) pk[i] = *(const u16x8*)(ksrc + i * 8);
#pragma unroll
    for (int i = 0; i < 4; ++i) pt[i] = *(const u16x8*)(tsrc + i * 8);
    if (tid < 128) sv = sqb[tid];

    f32x4 Oacc[4][4], lacc[4];
    const f32x4 z4 = {0.f, 0.f, 0.f, 0.f};
#pragma unroll
    for (int n = 0; n < 4; ++n) {
        lacc[n] = z4;
#pragma unroll
        for (int d = 0; d < 4; ++d) Oacc[d][n] = z4;
    }
    bf16x8 ones;
    {
        union { u16x8 u; bf16x8 b; } cv;
#pragma unroll
        for (int e = 0; e < 8; ++e) cv.u[e] = 0x3F80;
        ones = cv.b;
    }

    for (int j = 0; j < S_LEN / 128; ++j) {
        __syncthreads();
#pragma unroll
        for (int i = 0; i < 4; ++i)
            *(u16x8*)(Kt + kr * 64 + ((ks * 4 + i) ^ kswz) * 8) = pk[i];
#pragma unroll
        for (int i = 0; i < 4; ++i)
            *(u16x8*)(KtT + td * 128 + ((ts * 4 + i) ^ tswz) * 8) = pt[i];
        if (tid < 128) sql[tid] = sv;
        __syncthreads();

        int jn = (j + 1) & 15;
        {
            const u16* kn = ksrc + (size_t)jn * 128 * D_DIM;
            const u16* tn = tsrc + (size_t)jn * 128;
#pragma unroll
            for (int i = 0; i < 4; ++i) pk[i] = *(const u16x8*)(kn + i * 8);
#pragma unroll
            for (int i = 0; i < 4; ++i) pt[i] = *(const u16x8*)(tn + i * 8);
            if (tid < 128) sv = sqb[jn * 128 + tid];
        }

        // two key-half rounds: S^T (32 keys x 64 q) -> exp/pack -> PV
        for (int kt = 0; kt < 2; ++kt) {
            f32x4 sacc[2][4];
#pragma unroll
            for (int kbh = 0; kbh < 2; ++kbh)
#pragma unroll
                for (int nq = 0; nq < 4; ++nq) sacc[kbh][nq] = z4;
#pragma unroll
            for (int kbh = 0; kbh < 2; ++kbh) {
                int kro = krow00 + kt * 2048 + kbh * 256;
                bf16x8 a0 = *(const bf16x8*)(Kt + kro);
                bf16x8 a1 = *(const bf16x8*)(Kt + (kro ^ 32));
#pragma unroll
                for (int nq = 0; nq < 4; ++nq) {
                    sacc[kbh][nq] = MFMA16(a0, qb[nq][0], sacc[kbh][nq]);
                    sacc[kbh][nq] = MFMA16(a1, qb[nq][1], sacc[kbh][nq]);
                }
            }

            // hoist V-fragment LDS reads: latency hides under the exp chain
            bf16x8 va[4];
#pragma unroll
            for (int dblk = 0; dblk < 4; ++dblk)
                va[dblk] = *(const bf16x8*)(KtT + (vrow[dblk] ^ (kt * 32)));

            u32 pf[4][4];
#pragma unroll
            for (int kbh = 0; kbh < 2; ++kbh) {
                f32x4 sqv = *(const f32x4*)(sql + sq00 + kt * 32 + kbh * 4);
#pragma unroll
                for (int nq = 0; nq < 4; ++nq) {
                    float p0 = EXP2(fmaf(sacc[kbh][nq][0], C_QK, -sqv[0]));
                    float p1 = EXP2(fmaf(sacc[kbh][nq][1], C_QK, -sqv[1]));
                    float p2 = EXP2(fmaf(sacc[kbh][nq][2], C_QK, -sqv[2]));
                    float p3 = EXP2(fmaf(sacc[kbh][nq][3], C_QK, -sqv[3]));
                    pf[nq][kbh * 2]     = pack_bf(p0, p1);
                    pf[nq][kbh * 2 + 1] = pack_bf(p2, p3);
                }
            }

#pragma unroll
            for (int nq = 0; nq < 4; ++nq) {
                union { u32 u[4]; bf16x8 b; } pb;
#pragma unroll
                for (int i = 0; i < 4; ++i) pb.u[i] = pf[nq][i];
                lacc[nq] = MFMA16(ones, pb.b, lacc[nq]);   // key-sums, rows replicated
#pragma unroll
                for (int dblk = 0; dblk < 4; ++dblk)
                    Oacc[dblk][nq] = MFMA16(va[dblk], pb.b, Oacc[dblk][nq]);
            }
        }
    }

    // cross-wave (key-half) combine + epilogue
    __syncthreads();
    float* Obuf = (float*)smem;                 // [2][16][64] f32x4 = 32 KB
    float* lred = (float*)(smem + 32768);       // [2][4][64]
    if (wk == 1) {
#pragma unroll
        for (int dblk = 0; dblk < 4; ++dblk)
#pragma unroll
            for (int nq = 0; nq < 4; ++nq)
                *(f32x4*)(Obuf + ((wq * 16 + dblk * 4 + nq) * 64 + lane) * 4) = Oacc[dblk][nq];
#pragma unroll
        for (int nq = 0; nq < 4; ++nq)
            lred[(wq * 4 + nq) * 64 + lane] = lacc[nq][0];
    }
    __syncthreads();
    if (wk == 0) {
        float rinv[4];
#pragma unroll
        for (int nq = 0; nq < 4; ++nq)
            rinv[nq] = 1.f / (lacc[nq][0] + lred[(wq * 4 + nq) * 64 + lane]);
        u16* obase = attnO + (size_t)b * S_LEN * D_DIM + h * DHEAD;
#pragma unroll
        for (int dblk = 0; dblk < 4; ++dblk)
#pragma unroll
            for (int nq = 0; nq < 4; ++nq) {
                f32x4 o = Oacc[dblk][nq] + *(const f32x4*)(Obuf + ((wq * 16 + dblk * 4 + nq) * 64 + lane) * 4);
                int q = qt * 128 + wq * 64 + nq * 16 + col16;
                u16x4 pkk;
#pragma unroll
                for (int rr = 0; rr < 4; ++rr) pkk[rr] = f2bf(o[rr] * rinv[nq]);
                *(u16x4*)(obase + (size_t)q * D_DIM + dblk * 16 + quad * 4) = pkk;
            }
    }
}

// ---------------------------------------------------------------------------
// Output GEMM, 128x128 tile, 512 threads, grid (32,8):
// out[s,o] = x[s,o] + bout[o] + attnO·W2^T
__global__ __launch_bounds__(512, 4) void k_oproj(
    const u16* __restrict__ attnO, const u16* __restrict__ W2,
    const float* __restrict__ x, const float* __restrict__ bout, float* __restrict__ out) {
    __shared__ __align__(16) char smem[36864];
    u16* Al = (u16*)smem;              // [128][72]
    u16* Bl = (u16*)(smem + 18432);    // [128][72]
    const int tid = threadIdx.x, lane = tid & 63, w = tid >> 6;
    const int wm = w & 1, wn = w >> 1;
    const int col16 = lane & 15, quad = lane >> 4;
    const int bm = blockIdx.x, bn = blockIdx.y;

    f32x4 acc[4][2];
    const f32x4 z4 = {0.f, 0.f, 0.f, 0.f};
#pragma unroll
    for (int i = 0; i < 4; ++i)
#pragma unroll
        for (int j = 0; j < 2; ++j) acc[i][j] = z4;

    const int ar = tid >> 2, as = tid & 3;
    const u16* pa = attnO + (size_t)(bm * 128 + ar) * D_DIM + as * 16;
    const u16* pb = W2 + (size_t)(bn * 128 + ar) * D_DIM + as * 16;

    u16x8 ra[2], rb[2];
#pragma unroll
    for (int i = 0; i < 2; ++i) ra[i] = *(const u16x8*)(pa + i * 8);
#pragma unroll
    for (int i = 0; i < 2; ++i) rb[i] = *(const u16x8*)(pb + i * 8);

    for (int k0 = 0; k0 < D_DIM; k0 += 64) {
        __syncthreads();
#pragma unroll
        for (int i = 0; i < 2; ++i) *(u16x8*)&Al[ar * 72 + as * 16 + i * 8] = ra[i];
#pragma unroll
        for (int i = 0; i < 2; ++i) *(u16x8*)&Bl[ar * 72 + as * 16 + i * 8] = rb[i];
        __syncthreads();
        if (k0 + 64 < D_DIM) {
#pragma unroll
            for (int i = 0; i < 2; ++i) ra[i] = *(const u16x8*)(pa + k0 + 64 + i * 8);
#pragma unroll
            for (int i = 0; i < 2; ++i) rb[i] = *(const u16x8*)(pb + k0 + 64 + i * 8);
        }
#pragma unroll
        for (int kh = 0; kh < 2; ++kh) {
            bf16x8 af[4];
#pragma unroll
            for (int mt = 0; mt < 4; ++mt)
                af[mt] = *(const bf16x8*)&Al[(wm * 64 + mt * 16 + col16) * 72 + kh * 32 + quad * 8];
#pragma unroll
            for (int nt = 0; nt < 2; ++nt) {
                bf16x8 bfr = *(const bf16x8*)&Bl[(wn * 32 + nt * 16 + col16) * 72 + kh * 32 + quad * 8];
#pragma unroll
                for (int mt = 0; mt < 4; ++mt)
                    acc[mt][nt] = MFMA16(af[mt], bfr, acc[mt][nt]);
            }
        }
    }
#pragma unroll
    for (int nt = 0; nt < 2; ++nt) {
        int col = bn * 128 + wn * 32 + nt * 16 + col16;
        float bv = bout[col];
#pragma unroll
        for (int mt = 0; mt < 4; ++mt) {
            int row0 = bm * 128 + wm * 64 + mt * 16 + quad * 4;
#pragma unroll
            for (int rr = 0; rr < 4; ++rr) {
                size_t idx = (size_t)(row0 + rr) * D_DIM + col;
                out[idx] = acc[mt][nt][rr] + x[idx] + bv;
            }
        }
    }
}

// ---------------------------------------------------------------------------
extern "C" void kernel_launch(void* const* d_in, const int* in_sizes, int n_in,
                              void* d_out, int out_size, void* d_ws, size_t ws_size,
                              hipStream_t stream) {
    const float* x    = (const float*)d_in[0];
    const float* Wq   = (const float*)d_in[1];
    const float* bq   = (const float*)d_in[2];
    const float* Wv   = (const float*)d_in[3];
    const float* Wout = (const float*)d_in[4];
    const float* bout = (const float*)d_in[5];
    const int*   mask = (const int*)d_in[6];
    float* out = (float*)d_out;

    char* ws = (char*)d_ws;
    u16*   Qbf   = (u16*)(ws);                         // 8 MB
    u16*   QT    = (u16*)(ws + (8u << 20));            // 8 MB
    u16*   xb    = (u16*)(ws + (16u << 20));           // 8 MB (reused as attnO)
    u16*   wqb   = (u16*)(ws + (24u << 20));           // 2 MB
    u16*   W2    = (u16*)(ws + (26u << 20));           // 2 MB
    float* Mpart = (float*)(ws + (28u << 20));         // 1 MB (4 partials)
    float* sq05  = (float*)(ws + (29u << 20));         // 256 KB
    u16*   attnO = xb;   // xb dead after k_qproj

    k_cvt<<<dim3(2560), dim3(256), 0, stream>>>(x, Wq, xb, wqb);
    k_precomp_M<<<dim3(8, 16, 4), dim3(256), 0, stream>>>(Wq, Wv, Mpart);
    k_precomp_W2<<<dim3(16, 16), dim3(256), 0, stream>>>(Mpart, Wout, W2);
    k_qproj<<<dim3(32, 8), dim3(512), 0, stream>>>(xb, wqb, bq, mask, Qbf, QT, sq05);
    k_flash<<<dim3(512), dim3(256), 0, stream>>>(Qbf, QT, sq05, attnO);
    k_oproj<<<dim3(32, 8), dim3(512), 0, stream>>>(attnO, W2, x, bout, out);
}